// Round 19
// baseline (358.366 us; speedup 1.0000x reference)
//
#include <hip/hip_runtime.h>
#include <hip/hip_fp16.h>
#include <math.h>

static constexpr int F2 = 128, EMB = 320;

typedef _Float16 h8v __attribute__((ext_vector_type(8)));
typedef float f4v __attribute__((ext_vector_type(4)));

union F4H2 { float4 f; __half2 h[4]; };
union F2H2 { float2 f; __half2 h[2]; };

__device__ __forceinline__ __half2 shfl_xor_h2(__half2 v, int off) {
    union { __half2 h; float f; } u;
    u.h = v;
    u.f = __shfl_xor(u.f, off);
    return u.h;
}

__device__ __forceinline__ void esd(const int* src, const int* dst, int E, int e, int& s, int& d) {
    if (e < E) { s = src[e]; d = dst[e]; }
    else       { s = e - E; d = s; }
}

// ---------------- CSR build ----------------
__global__ void k_count(const int* __restrict__ src, const int* __restrict__ dst, int E, int Etot,
                        int* __restrict__ cnt) {
    int e = blockIdx.x * 256 + threadIdx.x;
    if (e >= Etot) return;
    int s, d;
    esd(src, dst, E, e, s, d);
    atomicAdd(&cnt[d], 1);
}

__global__ void k_scan1(const int* __restrict__ in, int* __restrict__ out, int* __restrict__ bsum,
                        int n) {
    __shared__ int tmp[256];
    int t = threadIdx.x;
    int gid = blockIdx.x * 256 + t;
    int v = gid < n ? in[gid] : 0;
    tmp[t] = v;
    __syncthreads();
    for (int off = 1; off < 256; off <<= 1) {
        int u = (t >= off) ? tmp[t - off] : 0;
        __syncthreads();
        tmp[t] += u;
        __syncthreads();
    }
    if (gid < n) out[gid] = tmp[t] - v;
    if (t == 255) bsum[blockIdx.x] = tmp[255];
}

__global__ void k_scan2(int* __restrict__ bsum, int nb) {
    __shared__ int tmp[256];
    __shared__ int carry;
    int t = threadIdx.x;
    if (t == 0) carry = 0;
    __syncthreads();
    for (int base = 0; base < nb; base += 256) {
        int i = base + t;
        int v = (i < nb) ? bsum[i] : 0;
        tmp[t] = v;
        __syncthreads();
        for (int off = 1; off < 256; off <<= 1) {
            int u = (t >= off) ? tmp[t - off] : 0;
            __syncthreads();
            tmp[t] += u;
            __syncthreads();
        }
        if (i < nb) bsum[i] = tmp[t] - v + carry;
        __syncthreads();
        if (t == 0) carry += tmp[255];
        __syncthreads();
    }
}

__global__ void k_scan3(int* __restrict__ out, const int* __restrict__ bsum, int n, int Etot,
                        int* __restrict__ rp_last, int* __restrict__ cur) {
    int gid = blockIdx.x * 256 + threadIdx.x;
    if (gid < n) {
        int v = out[gid] + bsum[blockIdx.x];
        out[gid] = v;
        cur[gid] = v;
    }
    if (gid == 0) rp_last[0] = Etot;
}

__global__ void k_scatter(const int* __restrict__ src, const int* __restrict__ dst, int E, int Etot,
                          int* __restrict__ cur, int* __restrict__ csrc) {
    int e = blockIdx.x * 256 + threadIdx.x;
    if (e >= Etot) return;
    int s, d;
    esd(src, dst, E, e, s, d);
    int pos = atomicAdd(&cur[d], 1);
    csrc[pos] = s;
}

// ---------------- merged weight prep ----------------
// job A: W1T [10][80][96] (<76800), job B: wes/wed [10][80] (next 800),
// job C: W2c [128][832]: W2c[c][ch*416+k] = W2[ch*390+k][c] (k<390, else 0)
__global__ void k_prep_w(const float* __restrict__ W1, const float* __restrict__ a1s,
                         const float* __restrict__ a1d, const float* __restrict__ W2,
                         __half* __restrict__ W1T, float* __restrict__ wes,
                         float* __restrict__ wed, __half* __restrict__ W2c) {
    int idx = blockIdx.x * 256 + threadIdx.x;
    if (idx < 76800) {
        int h = idx / (80 * 96), r = idx % (80 * 96), c = r / 96, k = r % 96;
        float v = (c < 78 && k < 78) ? W1[(size_t)k * 780 + h * 78 + c] : 0.f;
        W1T[idx] = __float2half(v);
    } else if (idx < 77600) {
        int j = idx - 76800;
        int h = j / 80, k = j % 80;
        float s = 0.f, d = 0.f;
        if (k < 78) {
            for (int f = 0; f < 78; f++) {
                float w = W1[(size_t)k * 780 + h * 78 + f];
                s = fmaf(w, a1s[h * 78 + f], s);
                d = fmaf(w, a1d[h * 78 + f], d);
            }
        }
        wes[j] = s;
        wed[j] = d;
    } else if (idx < 77600 + 128 * 832) {
        int j = idx - 77600;
        int c = j / 832, r = j % 832, ch = r / 416, k = r % 416;
        float v = (k < 390) ? W2[(size_t)(ch * 390 + k) * 128 + c] : 0.f;
        W2c[j] = __float2half(v);
    }
}

// xpk [N][64] half2: {x[c], x[c+64] or 0}
__global__ void k_prep_xpk(const float* __restrict__ x, __half2* __restrict__ xpk, int N) {
    int idx = blockIdx.x * 256 + threadIdx.x;
    if (idx >= N * 64) return;
    int n = idx >> 6, l = idx & 63;
    float lo = x[(size_t)n * 78 + l];
    float hi = (64 + l < 78) ? x[(size_t)n * 78 + 64 + l] : 0.f;
    xpk[idx] = __floats2half2_rn(lo, hi);
}

// es/ed for all 10 heads: esg/edg [N][16]
__global__ void k_coefx(const float* __restrict__ x, const float* __restrict__ wes,
                        const float* __restrict__ wed, float* __restrict__ esg,
                        float* __restrict__ edg, int N) {
    int n = blockIdx.x * 256 + threadIdx.x;
    if (n >= N) return;
    float es[10] = {}, ed[10] = {};
    const float* xr = x + (size_t)n * 78;
    for (int k = 0; k < 78; k++) {
        float xv = xr[k];
#pragma unroll
        for (int h = 0; h < 10; h++) {
            es[h] = fmaf(xv, wes[h * 80 + k], es[h]);
            ed[h] = fmaf(xv, wed[h * 80 + k], ed[h]);
        }
    }
#pragma unroll
    for (int h = 0; h < 10; h++) {
        esg[(size_t)n * 16 + h] = es[h];
        edg[(size_t)n * 16 + h] = ed[h];
    }
}

// ---------------- fused 10-head GAT on x -> xagg [N][10][80] fp16 ----------------
__global__ void k_gatx10(const int* __restrict__ rp, const int* __restrict__ csrc,
                         const float* __restrict__ esg, const float* __restrict__ edg,
                         const __half2* __restrict__ xpk, __half* __restrict__ xagg, int N) {
    __shared__ __align__(16) __half2 pl[4][64][12];
    __shared__ __align__(16) int sl[4][64];
    int w = threadIdx.x >> 6, lane = threadIdx.x & 63;
    int node = blockIdx.x * 4 + w;
    if (node >= N) return;
    int beg = rp[node], end = rp[node + 1];
    int deg = end - beg;

    float edn[10];
    {
        const float* ep = edg + (size_t)node * 16;
        float4 a = *(const float4*)ep, b = *(const float4*)(ep + 4);
        float2 c = *(const float2*)(ep + 8);
        edn[0] = a.x; edn[1] = a.y; edn[2] = a.z; edn[3] = a.w;
        edn[4] = b.x; edn[5] = b.y; edn[6] = b.z; edn[7] = b.w;
        edn[8] = c.x; edn[9] = c.y;
    }

    __half2 acc[10];
#pragma unroll
    for (int h = 0; h < 10; h++) acc[h] = __floats2half2_rn(0.f, 0.f);

#define PASSC_BODY(LIMIT)                                                          \
    for (int i0 = 0; i0 < (LIMIT); i0 += 4) {                                      \
        int4 s4 = *(const int4*)&sl[w][i0];                                        \
        __half2 xr0 = xpk[(size_t)s4.x * 64 + lane];                               \
        __half2 xr1 = xpk[(size_t)s4.y * 64 + lane];                               \
        __half2 xr2 = xpk[(size_t)s4.z * 64 + lane];                               \
        __half2 xr3 = xpk[(size_t)s4.w * 64 + lane];                               \
        _Pragma("unroll")                                                          \
        for (int j = 0; j < 4; j++) {                                              \
            F4H2 qa, qb; F2H2 qc;                                                  \
            qa.f = *(const float4*)&pl[w][i0 + j][0];                              \
            qb.f = *(const float4*)&pl[w][i0 + j][4];                              \
            qc.f = *(const float2*)&pl[w][i0 + j][8];                              \
            __half2 xr = (j == 0) ? xr0 : (j == 1) ? xr1 : (j == 2) ? xr2 : xr3;   \
            acc[0] = __hfma2(qa.h[0], xr, acc[0]);                                 \
            acc[1] = __hfma2(qa.h[1], xr, acc[1]);                                 \
            acc[2] = __hfma2(qa.h[2], xr, acc[2]);                                 \
            acc[3] = __hfma2(qa.h[3], xr, acc[3]);                                 \
            acc[4] = __hfma2(qb.h[0], xr, acc[4]);                                 \
            acc[5] = __hfma2(qb.h[1], xr, acc[5]);                                 \
            acc[6] = __hfma2(qb.h[2], xr, acc[6]);                                 \
            acc[7] = __hfma2(qb.h[3], xr, acc[7]);                                 \
            acc[8] = __hfma2(qc.h[0], xr, acc[8]);                                 \
            acc[9] = __hfma2(qc.h[1], xr, acc[9]);                                 \
        }                                                                          \
    }

#define STASH(PVEC)                                                                \
    {                                                                              \
        F4H2 wa, wb; F2H2 wc;                                                      \
        _Pragma("unroll")                                                          \
        for (int h = 0; h < 4; h++) wa.h[h] = __float2half2_rn(PVEC[h]);           \
        _Pragma("unroll")                                                          \
        for (int h = 0; h < 4; h++) wb.h[h] = __float2half2_rn(PVEC[4 + h]);       \
        wc.h[0] = __float2half2_rn(PVEC[8]);                                       \
        wc.h[1] = __float2half2_rn(PVEC[9]);                                       \
        *(float4*)&pl[w][lane][0] = wa.f;                                          \
        *(float4*)&pl[w][lane][4] = wb.f;                                          \
        *(float2*)&pl[w][lane][8] = wc.f;                                          \
        sl[w][lane] = s;                                                           \
    }

    if (deg <= 64) {
        bool act = lane < deg;
        int s = act ? csrc[beg + lane] : 0;
        float p[10];
        if (act) {
            const float* sp = esg + (size_t)s * 16;
            float4 a = *(const float4*)sp, b = *(const float4*)(sp + 4);
            float2 c = *(const float2*)(sp + 8);
            float v[10];
            v[0] = a.x + edn[0]; v[1] = a.y + edn[1]; v[2] = a.z + edn[2]; v[3] = a.w + edn[3];
            v[4] = b.x + edn[4]; v[5] = b.y + edn[5]; v[6] = b.z + edn[6]; v[7] = b.w + edn[7];
            v[8] = c.x + edn[8]; v[9] = c.y + edn[9];
#pragma unroll
            for (int h = 0; h < 10; h++) {
                float vv = v[h] >= 0.f ? v[h] : 0.2f * v[h];
                p[h] = __expf(vv);
            }
        } else {
#pragma unroll
            for (int h = 0; h < 10; h++) p[h] = 0.f;
        }
        __half2 sh[5];
#pragma unroll
        for (int j = 0; j < 5; j++) sh[j] = __floats2half2_rn(p[2 * j], p[2 * j + 1]);
        int start = (deg <= 16) ? 8 : 32;
        for (int off = start; off; off >>= 1) {
#pragma unroll
            for (int j = 0; j < 5; j++) sh[j] = __hadd2(sh[j], shfl_xor_h2(sh[j], off));
        }
#pragma unroll
        for (int j = 0; j < 5; j++) {
            float2 f = __half22float2(sh[j]);
            p[2 * j] *= 1.f / f.x;
            p[2 * j + 1] *= 1.f / f.y;
        }
        STASH(p)
        PASSC_BODY(deg)
    } else {
        float ssf[10] = {};
        for (int cb = beg; cb < end; cb += 64) {
            int e = cb + lane;
            bool act = e < end;
            int si = act ? csrc[e] : 0;
            if (act) {
                const float* sp = esg + (size_t)si * 16;
#pragma unroll
                for (int h = 0; h < 10; h++) {
                    float vv = sp[h] + edn[h];
                    vv = vv >= 0.f ? vv : 0.2f * vv;
                    ssf[h] += __expf(vv);
                }
            }
        }
#pragma unroll
        for (int off = 32; off; off >>= 1) {
#pragma unroll
            for (int h = 0; h < 10; h++) ssf[h] += __shfl_xor(ssf[h], off);
        }
        float inv[10];
#pragma unroll
        for (int h = 0; h < 10; h++) inv[h] = 1.f / ssf[h];

        for (int cb = beg; cb < end; cb += 64) {
            int cnt = min(64, end - cb);
            int e = cb + lane;
            bool act = e < end;
            int s = act ? csrc[e] : 0;
            float p[10];
            if (act) {
                const float* sp = esg + (size_t)s * 16;
#pragma unroll
                for (int h = 0; h < 10; h++) {
                    float vv = sp[h] + edn[h];
                    vv = vv >= 0.f ? vv : 0.2f * vv;
                    p[h] = __expf(vv) * inv[h];
                }
            } else {
#pragma unroll
                for (int h = 0; h < 10; h++) p[h] = 0.f;
            }
            STASH(p)
            PASSC_BODY(cnt)
        }
    }
#undef PASSC_BODY
#undef STASH

    __half* op = xagg + (size_t)node * 800;
#pragma unroll
    for (int h = 0; h < 10; h++) {
        __half* hp = op + h * 80;
        hp[lane] = __low2half(acc[h]);
        if (lane < 16) hp[64 + lane] = __high2half(acc[h]);
    }
}

// ---------------- fused GEMM chain: 256 thr, 2 chunks x 5 heads @ stride 78, 13.3KB LDS ----------------
// 8 blocks/CU (thread-capped) = 32 waves/CU cap. 4 barriers; phases 15-30 / 26 MFMA.
__global__ __launch_bounds__(256) void k_gemmQ(const __half* __restrict__ xagg,
                                               const __half* __restrict__ W1T,
                                               const float* __restrict__ b1,
                                               const __half* __restrict__ W2c,
                                               const float* __restrict__ a2s,
                                               const float* __restrict__ a2d,
                                               __half* __restrict__ h216,
                                               float* __restrict__ es2,
                                               float* __restrict__ ed2, int N) {
    constexpr int LQ = 416;  // halfs; 832B row stride (16B aligned)
    __shared__ __align__(16) _Float16 qlds[16 * LQ];  // 13.3 KB
    __shared__ float sered[4][2][16];
    int w = threadIdx.x >> 6, lane = threadIdx.x & 63;
    int row0 = blockIdx.x * 16;
    int col16 = lane & 15, grp = lane >> 4;
    int ko = grp * 8;
    int rbase = grp * 4;
    int ar = min(row0 + col16, N - 1);

    // zero pad cols 390..415 (persist across chunks; data cols overwritten each chunk)
    for (int i = threadIdx.x; i < 16 * 26; i += 256) {
        int r = i / 26, c = 390 + i % 26;
        qlds[r * LQ + c] = (_Float16)0.f;
    }

    const _Float16* Ab = (const _Float16*)xagg + (size_t)ar * 800 + ko;
    const _Float16* Aq = qlds + (size_t)col16 * LQ + ko;
    f4v acc[2] = {};

#pragma unroll
    for (int ch = 0; ch < 2; ch++) {
        // ---- phase 1: heads hh = w, w+4 (wave0: {0,4}; waves1-3: one head each) ----
        for (int hh = w; hh < 5; hh += 4) {
            int h = ch * 5 + hh;
            f4v acc1[5] = {};
            const _Float16* Ap = Ab + h * 80;
            const _Float16* Bp = (const _Float16*)W1T + ((size_t)h * 80 + col16) * 96 + ko;
#pragma unroll
            for (int ks = 0; ks < 3; ks++) {
                h8v a = *(const h8v*)(Ap + ks * 32);  // ks=2 overreads; W1T zeros cover
#pragma unroll
                for (int t = 0; t < 5; t++) {
                    h8v b = *(const h8v*)(Bp + (size_t)t * 16 * 96 + ks * 32);
                    acc1[t] = __builtin_amdgcn_mfma_f32_16x16x32_f16(a, b, acc1[t], 0, 0, 0);
                }
            }
#pragma unroll
            for (int t = 0; t < 5; t++) {
                int c = t * 16 + col16;
                if (c < 78) {
                    float bias = b1[h * 78 + c];
#pragma unroll
                    for (int r = 0; r < 4; r++) {
                        float v = acc1[t][r] + bias;
                        float e = v > 0.f ? v : (__expf(v) - 1.f);
                        qlds[(rbase + r) * LQ + hh * 78 + c] = (_Float16)e;
                    }
                }
            }
        }
        __syncthreads();
        // ---- phase 2: this chunk's K=416 (13 ks), t-tiles 2w..2w+1 ----
        const _Float16* Bq = (const _Float16*)W2c + ((size_t)(w * 2) * 16 + col16) * 832 +
                             ch * 416 + ko;
        for (int ks = 0; ks < 13; ks++) {
            h8v a = *(const h8v*)(Aq + ks * 32);
#pragma unroll
            for (int t = 0; t < 2; t++) {
                h8v b = *(const h8v*)(Bq + (size_t)t * 16 * 832 + ks * 32);
                acc[t] = __builtin_amdgcn_mfma_f32_16x16x32_f16(a, b, acc[t], 0, 0, 0);
            }
        }
        __syncthreads();
    }

    // ---- epilogue: h216 + fused es2/ed2 ----
    float wa[2], wb[2];
#pragma unroll
    for (int t = 0; t < 2; t++) {
        wa[t] = a2s[(w * 2 + t) * 16 + col16];
        wb[t] = a2d[(w * 2 + t) * 16 + col16];
    }
#pragma unroll
    for (int r = 0; r < 4; r++) {
        int n = row0 + rbase + r;
        float se = 0.f, sd = 0.f;
#pragma unroll
        for (int t = 0; t < 2; t++) {
            float v = acc[t][r];
            se = fmaf(v, wa[t], se);
            sd = fmaf(v, wb[t], sd);
            if (n < N) h216[(size_t)n * 128 + (w * 2 + t) * 16 + col16] = __float2half(v);
        }
#pragma unroll
        for (int off = 1; off < 16; off <<= 1) {
            se += __shfl_xor(se, off);
            sd += __shfl_xor(sd, off);
        }
        if (col16 == 0) {
            sered[w][0][rbase + r] = se;
            sered[w][1][rbase + r] = sd;
        }
    }
    __syncthreads();
    if (threadIdx.x < 16) {
        int n = row0 + threadIdx.x;
        if (n < N) {
            es2[n] = sered[0][0][threadIdx.x] + sered[1][0][threadIdx.x] +
                     sered[2][0][threadIdx.x] + sered[3][0][threadIdx.x];
            ed2[n] = sered[0][1][threadIdx.x] + sered[1][1][threadIdx.x] +
                     sered[2][1][threadIdx.x] + sered[3][1][threadIdx.x];
        }
    }
}

// ---------------- layer-2 GAT + relu + block-pooled max -> gb ----------------
__global__ void k_gatP(const int* __restrict__ rp, const int* __restrict__ csrc,
                       const float* __restrict__ es, const float* __restrict__ ed,
                       const __half2* __restrict__ h216, const float* __restrict__ b2,
                       const int* __restrict__ batch, unsigned* __restrict__ gb, int N) {
    __shared__ float red[4][128];
    __shared__ int bids[4];
    __shared__ __align__(16) __half2 plP[4][64];
    __shared__ __align__(16) int slP[4][64];
    int w = threadIdx.x >> 6, lane = threadIdx.x & 63;
    int node = blockIdx.x * 4 + w;
    bool valid = node < N;

    __half2 acc = __floats2half2_rn(0.f, 0.f);
    int bid = -1;

#define PASSC2(LIMIT)                                                      \
    for (int i0 = 0; i0 < (LIMIT); i0 += 4) {                              \
        int4 s4 = *(const int4*)&slP[w][i0];                               \
        F4H2 q; q.f = *(const float4*)&plP[w][i0];                         \
        __half2 f0 = h216[(size_t)s4.x * 64 + lane];                       \
        __half2 f1 = h216[(size_t)s4.y * 64 + lane];                       \
        __half2 f2 = h216[(size_t)s4.z * 64 + lane];                       \
        __half2 f3 = h216[(size_t)s4.w * 64 + lane];                       \
        acc = __hfma2(q.h[0], f0, acc);                                    \
        acc = __hfma2(q.h[1], f1, acc);                                    \
        acc = __hfma2(q.h[2], f2, acc);                                    \
        acc = __hfma2(q.h[3], f3, acc);                                    \
    }

    if (valid) {
        int beg = rp[node], end = rp[node + 1];
        int deg = end - beg;
        float edn = ed[node];
        bid = batch[node];

        if (deg <= 64) {
            bool act = lane < deg;
            int s = act ? csrc[beg + lane] : 0;
            float p = 0.f;
            if (act) {
                float v = es[s] + edn;
                v = v >= 0.f ? v : 0.2f * v;
                p = __expf(v);
            }
            float ss = p;
            int start = (deg <= 16) ? 8 : 32;
            for (int off = start; off; off >>= 1) ss += __shfl_xor(ss, off);
            p *= 1.f / ss;
            plP[w][lane] = __float2half2_rn(p);
            slP[w][lane] = s;
            PASSC2(deg)
        } else {
            float ss = 0.f;
            for (int cb = beg; cb < end; cb += 64) {
                int e = cb + lane;
                bool act = e < end;
                int s = act ? csrc[e] : 0;
                if (act) {
                    float v = es[s] + edn;
                    v = v >= 0.f ? v : 0.2f * v;
                    ss += __expf(v);
                }
            }
#pragma unroll
            for (int off = 32; off; off >>= 1) ss += __shfl_xor(ss, off);
            float inv = 1.f / ss;
            for (int cb = beg; cb < end; cb += 64) {
                int cnt = min(64, end - cb);
                int e = cb + lane;
                bool act = e < end;
                int s = act ? csrc[e] : 0;
                float p = 0.f;
                if (act) {
                    float v = es[s] + edn;
                    v = v >= 0.f ? v : 0.2f * v;
                    p = __expf(v) * inv;
                }
                plP[w][lane] = __float2half2_rn(p);
                slP[w][lane] = s;
                PASSC2(cnt)
            }
        }
    }
#undef PASSC2

    float2 af = __half22float2(acc);
    red[w][2 * lane]     = valid ? fmaxf(af.x + b2[2 * lane], 0.f) : 0.f;
    red[w][2 * lane + 1] = valid ? fmaxf(af.y + b2[2 * lane + 1], 0.f) : 0.f;
    if (lane == 0) bids[w] = valid ? bid : -1;
    __syncthreads();
    if (threadIdx.x < 128) {
        int c = threadIdx.x;
        int b0 = bids[0];
        bool same = (bids[1] == b0) && (bids[2] == b0) && (bids[3] == b0);
        if (same && b0 >= 0) {
            float m = fmaxf(fmaxf(red[0][c], red[1][c]), fmaxf(red[2][c], red[3][c]));
            atomicMax(&gb[(size_t)b0 * 128 + c], __float_as_uint(m));
        } else {
#pragma unroll
            for (int w2 = 0; w2 < 4; w2++) {
                if (bids[w2] >= 0)
                    atomicMax(&gb[(size_t)bids[w2] * 128 + c], __float_as_uint(red[w2][c]));
            }
        }
    }
}

// ---------------- fused head part 1 ----------------
__global__ void k_head_gxt(const unsigned* __restrict__ gbits, const float* __restrict__ Wg,
                           const float* __restrict__ bg, const float* __restrict__ te,
                           const float* __restrict__ Wxt, const float* __restrict__ bxt,
                           const float* __restrict__ gamma, const float* __restrict__ beta,
                           const float* __restrict__ rmean, const float* __restrict__ rvar,
                           float* __restrict__ xc) {
    __shared__ float sg[F2];
    __shared__ float st[EMB];
    int b = blockIdx.x, t = threadIdx.x;
    if (t < 128) {
        sg[t] = __uint_as_float(gbits[(size_t)b * F2 + t]);
    } else {
        for (int k = t - 128; k < EMB; k += 128) st[k] = te[(size_t)b * EMB + k];
    }
    __syncthreads();
    if (t < 128) {
        float acc = bg[t];
        for (int k = 0; k < F2; k++) acc = fmaf(sg[k], Wg[k * F2 + t], acc);
        xc[(size_t)b * 256 + t] = fmaxf(acc, 0.f);
    } else {
        int c = t - 128;
        float acc = bxt[c];
        for (int k = 0; k < EMB; k++) acc = fmaf(st[k], Wxt[k * F2 + c], acc);
        acc = (acc - rmean[c]) * rsqrtf(rvar[c] + 1e-5f) * gamma[c] + beta[c];
        xc[(size_t)b * 256 + 128 + c] = fmaxf(acc, 0.f);
    }
}

// ---------------- fused head part 2 ----------------
__global__ void k_head_mlp(const float* __restrict__ xc, const float* __restrict__ Wf1,
                           const float* __restrict__ bf1, const float* __restrict__ Wf2,
                           const float* __restrict__ bf2, const float* __restrict__ Wo,
                           const float* __restrict__ bo, float* __restrict__ out) {
    __shared__ float s0[256];
    __shared__ float s1[1024];
    int b = blockIdx.x, t = threadIdx.x;
    s0[t] = xc[(size_t)b * 256 + t];
    __syncthreads();
    for (int col = t; col < 1024; col += 256) {
        float acc = bf1[col];
        for (int k = 0; k < 256; k++) acc = fmaf(s0[k], Wf1[k * 1024 + col], acc);
        s1[col] = fmaxf(acc, 0.f);
    }
    __syncthreads();
    {
        float acc = bf2[t];
        for (int k = 0; k < 1024; k++) acc = fmaf(s1[k], Wf2[k * 256 + t], acc);
        float v = fmaxf(acc, 0.f);
        __syncthreads();
        s0[t] = v * Wo[t];
    }
    __syncthreads();
    if (t < 64) {
        float acc = s0[t] + s0[64 + t] + s0[128 + t] + s0[192 + t];
        for (int off = 32; off; off >>= 1) acc += __shfl_down(acc, off);
        if (t == 0) out[b] = acc + bo[0];
    }
}

extern "C" void kernel_launch(void* const* d_in, const int* in_sizes, int n_in,
                              void* d_out, int out_size, void* d_ws, size_t ws_size,
                              hipStream_t stream) {
    const float* x     = (const float*)d_in[0];
    const int*   ei    = (const int*)d_in[1];
    const int*   batch = (const int*)d_in[2];
    const float* te    = (const float*)d_in[3];
    const float* W1    = (const float*)d_in[4];
    const float* a1s   = (const float*)d_in[5];
    const float* a1d   = (const float*)d_in[6];
    const float* b1    = (const float*)d_in[7];
    const float* W2    = (const float*)d_in[8];
    const float* a2s   = (const float*)d_in[9];
    const float* a2d   = (const float*)d_in[10];
    const float* b2    = (const float*)d_in[11];
    const float* Wg    = (const float*)d_in[12];
    const float* bg    = (const float*)d_in[13];
    const float* Wxt   = (const float*)d_in[14];
    const float* bxt   = (const float*)d_in[15];
    const float* gamma = (const float*)d_in[16];
    const float* beta  = (const float*)d_in[17];
    const float* rmean = (const float*)d_in[18];
    const float* rvar  = (const float*)d_in[19];
    const float* Wf1   = (const float*)d_in[20];
    const float* bf1   = (const float*)d_in[21];
    const float* Wf2   = (const float*)d_in[22];
    const float* bf2   = (const float*)d_in[23];
    const float* Wo    = (const float*)d_in[24];
    const float* bo    = (const float*)d_in[25];

    const int N = in_sizes[0] / 78;
    const int E = in_sizes[1] / 2;
    const int B = in_sizes[3] / EMB;
    const int Etot = E + N;
    const int* src = ei;
    const int* dst = ei + E;

    char* p = (char*)d_ws;
    auto alloc = [&](size_t bytes) -> void* {
        void* r = p;
        p += (bytes + 255) & ~(size_t)255;
        return r;
    };
    __half2*  xpk  = (__half2*)alloc((size_t)N * 64 * 4);
    __half*   xagg = (__half*)alloc((size_t)N * 800 * 2 + 256);
    __half*   h216 = (__half*)alloc((size_t)N * 128 * 2);
    float*    esg  = (float*)alloc((size_t)N * 16 * 4);
    float*    edg  = (float*)alloc((size_t)N * 16 * 4);
    float*    es2  = (float*)alloc((size_t)N * 4);
    float*    ed2  = (float*)alloc((size_t)N * 4);
    __half*   W1T  = (__half*)alloc((size_t)10 * 80 * 96 * 2);
    __half*   W2c  = (__half*)alloc((size_t)128 * 832 * 2);
    float*    wes  = (float*)alloc((size_t)800 * 4);
    float*    wed  = (float*)alloc((size_t)800 * 4);
    int*      cnt  = (int*)alloc((size_t)N * 4);
    int*      rp   = (int*)alloc((size_t)(N + 1) * 4);
    int*      cur  = (int*)alloc((size_t)N * 4);
    int*      csrc = (int*)alloc((size_t)Etot * 4);
    int*      bsum = (int*)alloc((size_t)1024 * 4);
    unsigned* gb   = (unsigned*)alloc((size_t)B * F2 * 4);
    float*    xc   = (float*)alloc((size_t)B * 256 * 4);

    auto gsz = [](long long t) { return (int)((t + 255) / 256); };
    const int nb = gsz(N);
    const int nwave = (N + 3) / 4;
    const int nrow16 = (N + 15) / 16;

    // ---- CSR build ----
    hipMemsetAsync(cnt, 0, (size_t)N * 4, stream);
    k_count<<<gsz(Etot), 256, 0, stream>>>(src, dst, E, Etot, cnt);
    k_scan1<<<nb, 256, 0, stream>>>(cnt, rp, bsum, N);
    k_scan2<<<1, 256, 0, stream>>>(bsum, nb);
    k_scan3<<<nb, 256, 0, stream>>>(rp, bsum, N, Etot, rp + N, cur);
    k_scatter<<<gsz(Etot), 256, 0, stream>>>(src, dst, E, Etot, cur, csrc);

    // ---- prep ----
    k_prep_w<<<gsz(77600 + 128 * 832), 256, 0, stream>>>(W1, a1s, a1d, W2, W1T, wes, wed, W2c);
    k_prep_xpk<<<gsz((long long)N * 64), 256, 0, stream>>>(x, xpk, N);
    k_coefx<<<nb, 256, 0, stream>>>(x, wes, wed, esg, edg, N);
    hipMemsetAsync(gb, 0, (size_t)B * F2 * 4, stream);

    // ---- GAT layer 1 (all 10 heads) ----
    k_gatx10<<<nwave, 256, 0, stream>>>(rp, csrc, esg, edg, xpk, xagg, N);

    // ---- fused GEMM chain (2 chunks, 13.3KB LDS, 256 threads) ----
    k_gemmQ<<<nrow16, 256, 0, stream>>>(xagg, W1T, b1, W2c, a2s, a2d, h216, es2, ed2, N);

    // ---- GAT layer 2 + fused pool ----
    k_gatP<<<nwave, 256, 0, stream>>>(rp, csrc, es2, ed2, (const __half2*)h216, b2, batch, gb, N);

    // ---- head (fused: 2 kernels) ----
    k_head_gxt<<<B, 256, 0, stream>>>(gb, Wg, bg, te, Wxt, bxt, gamma, beta, rmean, rvar, xc);
    k_head_mlp<<<B, 256, 0, stream>>>(xc, Wf1, bf1, Wf2, bf2, Wo, bo, (float*)d_out);
}

// Round 20
// 328.862 us; speedup vs baseline: 1.0897x; 1.0897x over previous
//
#include <hip/hip_runtime.h>
#include <hip/hip_fp16.h>
#include <math.h>

static constexpr int F2 = 128, EMB = 320;

typedef _Float16 h8v __attribute__((ext_vector_type(8)));
typedef float f4v __attribute__((ext_vector_type(4)));

union F4H2 { float4 f; __half2 h[4]; };
union F2H2 { float2 f; __half2 h[2]; };

__device__ __forceinline__ __half2 shfl_xor_h2(__half2 v, int off) {
    union { __half2 h; float f; } u;
    u.h = v;
    u.f = __shfl_xor(u.f, off);
    return u.h;
}

__device__ __forceinline__ void esd(const int* src, const int* dst, int E, int e, int& s, int& d) {
    if (e < E) { s = src[e]; d = dst[e]; }
    else       { s = e - E; d = s; }
}

// ---------------- CSR build ----------------
__global__ void k_count(const int* __restrict__ src, const int* __restrict__ dst, int E, int Etot,
                        int* __restrict__ cnt) {
    int e = blockIdx.x * 256 + threadIdx.x;
    if (e >= Etot) return;
    int s, d;
    esd(src, dst, E, e, s, d);
    atomicAdd(&cnt[d], 1);
}

__global__ void k_scan1(const int* __restrict__ in, int* __restrict__ out, int* __restrict__ bsum,
                        int n) {
    __shared__ int tmp[256];
    int t = threadIdx.x;
    int gid = blockIdx.x * 256 + t;
    int v = gid < n ? in[gid] : 0;
    tmp[t] = v;
    __syncthreads();
    for (int off = 1; off < 256; off <<= 1) {
        int u = (t >= off) ? tmp[t - off] : 0;
        __syncthreads();
        tmp[t] += u;
        __syncthreads();
    }
    if (gid < n) out[gid] = tmp[t] - v;
    if (t == 255) bsum[blockIdx.x] = tmp[255];
}

__global__ void k_scan2(int* __restrict__ bsum, int nb) {
    __shared__ int tmp[256];
    __shared__ int carry;
    int t = threadIdx.x;
    if (t == 0) carry = 0;
    __syncthreads();
    for (int base = 0; base < nb; base += 256) {
        int i = base + t;
        int v = (i < nb) ? bsum[i] : 0;
        tmp[t] = v;
        __syncthreads();
        for (int off = 1; off < 256; off <<= 1) {
            int u = (t >= off) ? tmp[t - off] : 0;
            __syncthreads();
            tmp[t] += u;
            __syncthreads();
        }
        if (i < nb) bsum[i] = tmp[t] - v + carry;
        __syncthreads();
        if (t == 0) carry += tmp[255];
        __syncthreads();
    }
}

__global__ void k_scan3(int* __restrict__ out, const int* __restrict__ bsum, int n, int Etot,
                        int* __restrict__ rp_last, int* __restrict__ cur) {
    int gid = blockIdx.x * 256 + threadIdx.x;
    if (gid < n) {
        int v = out[gid] + bsum[blockIdx.x];
        out[gid] = v;
        cur[gid] = v;
    }
    if (gid == 0) rp_last[0] = Etot;
}

__global__ void k_scatter(const int* __restrict__ src, const int* __restrict__ dst, int E, int Etot,
                          int* __restrict__ cur, int* __restrict__ csrc) {
    int e = blockIdx.x * 256 + threadIdx.x;
    if (e >= Etot) return;
    int s, d;
    esd(src, dst, E, e, s, d);
    int pos = atomicAdd(&cur[d], 1);
    csrc[pos] = s;
}

// ---------------- merged weight prep ----------------
__global__ void k_prep_w(const float* __restrict__ W1, const float* __restrict__ a1s,
                         const float* __restrict__ a1d, const float* __restrict__ W2,
                         __half* __restrict__ W1T, float* __restrict__ wes,
                         float* __restrict__ wed, __half* __restrict__ W2T) {
    int idx = blockIdx.x * 256 + threadIdx.x;
    if (idx < 76800) {
        int h = idx / (80 * 96), r = idx % (80 * 96), c = r / 96, k = r % 96;
        float v = (c < 78 && k < 78) ? W1[(size_t)k * 780 + h * 78 + c] : 0.f;
        W1T[idx] = __float2half(v);
    } else if (idx < 77600) {
        int j = idx - 76800;
        int h = j / 80, k = j % 80;
        float s = 0.f, d = 0.f;
        if (k < 78) {
            for (int f = 0; f < 78; f++) {
                float w = W1[(size_t)k * 780 + h * 78 + f];
                s = fmaf(w, a1s[h * 78 + f], s);
                d = fmaf(w, a1d[h * 78 + f], d);
            }
        }
        wes[j] = s;
        wed[j] = d;
    } else if (idx < 77600 + 128 * 800) {
        int j = idx - 77600;
        int c = j / 800, k = j % 800;
        float v = (k < 780) ? W2[(size_t)k * 128 + c] : 0.f;
        W2T[j] = __float2half(v);
    }
}

// xpk [N][64] half2: {x[c], x[c+64] or 0}
__global__ void k_prep_xpk(const float* __restrict__ x, __half2* __restrict__ xpk, int N) {
    int idx = blockIdx.x * 256 + threadIdx.x;
    if (idx >= N * 64) return;
    int n = idx >> 6, l = idx & 63;
    float lo = x[(size_t)n * 78 + l];
    float hi = (64 + l < 78) ? x[(size_t)n * 78 + 64 + l] : 0.f;
    xpk[idx] = __floats2half2_rn(lo, hi);
}

// es/ed for all 10 heads: esg/edg [N][16]
__global__ void k_coefx(const float* __restrict__ x, const float* __restrict__ wes,
                        const float* __restrict__ wed, float* __restrict__ esg,
                        float* __restrict__ edg, int N) {
    int n = blockIdx.x * 256 + threadIdx.x;
    if (n >= N) return;
    float es[10] = {}, ed[10] = {};
    const float* xr = x + (size_t)n * 78;
    for (int k = 0; k < 78; k++) {
        float xv = xr[k];
#pragma unroll
        for (int h = 0; h < 10; h++) {
            es[h] = fmaf(xv, wes[h * 80 + k], es[h]);
            ed[h] = fmaf(xv, wed[h * 80 + k], ed[h]);
        }
    }
#pragma unroll
    for (int h = 0; h < 10; h++) {
        esg[(size_t)n * 16 + h] = es[h];
        edg[(size_t)n * 16 + h] = ed[h];
    }
}

// ---------------- fused 10-head GAT on x -> xagg [N][10][80] fp16 ----------------
__global__ void k_gatx10(const int* __restrict__ rp, const int* __restrict__ csrc,
                         const float* __restrict__ esg, const float* __restrict__ edg,
                         const __half2* __restrict__ xpk, __half* __restrict__ xagg, int N) {
    __shared__ __align__(16) __half2 pl[4][64][12];
    __shared__ __align__(16) int sl[4][64];
    int w = threadIdx.x >> 6, lane = threadIdx.x & 63;
    int node = blockIdx.x * 4 + w;
    if (node >= N) return;
    int beg = rp[node], end = rp[node + 1];
    int deg = end - beg;

    float edn[10];
    {
        const float* ep = edg + (size_t)node * 16;
        float4 a = *(const float4*)ep, b = *(const float4*)(ep + 4);
        float2 c = *(const float2*)(ep + 8);
        edn[0] = a.x; edn[1] = a.y; edn[2] = a.z; edn[3] = a.w;
        edn[4] = b.x; edn[5] = b.y; edn[6] = b.z; edn[7] = b.w;
        edn[8] = c.x; edn[9] = c.y;
    }

    __half2 acc[10];
#pragma unroll
    for (int h = 0; h < 10; h++) acc[h] = __floats2half2_rn(0.f, 0.f);

#define PASSC_BODY(LIMIT)                                                          \
    for (int i0 = 0; i0 < (LIMIT); i0 += 4) {                                      \
        int4 s4 = *(const int4*)&sl[w][i0];                                        \
        __half2 xr0 = xpk[(size_t)s4.x * 64 + lane];                               \
        __half2 xr1 = xpk[(size_t)s4.y * 64 + lane];                               \
        __half2 xr2 = xpk[(size_t)s4.z * 64 + lane];                               \
        __half2 xr3 = xpk[(size_t)s4.w * 64 + lane];                               \
        _Pragma("unroll")                                                          \
        for (int j = 0; j < 4; j++) {                                              \
            F4H2 qa, qb; F2H2 qc;                                                  \
            qa.f = *(const float4*)&pl[w][i0 + j][0];                              \
            qb.f = *(const float4*)&pl[w][i0 + j][4];                              \
            qc.f = *(const float2*)&pl[w][i0 + j][8];                              \
            __half2 xr = (j == 0) ? xr0 : (j == 1) ? xr1 : (j == 2) ? xr2 : xr3;   \
            acc[0] = __hfma2(qa.h[0], xr, acc[0]);                                 \
            acc[1] = __hfma2(qa.h[1], xr, acc[1]);                                 \
            acc[2] = __hfma2(qa.h[2], xr, acc[2]);                                 \
            acc[3] = __hfma2(qa.h[3], xr, acc[3]);                                 \
            acc[4] = __hfma2(qb.h[0], xr, acc[4]);                                 \
            acc[5] = __hfma2(qb.h[1], xr, acc[5]);                                 \
            acc[6] = __hfma2(qb.h[2], xr, acc[6]);                                 \
            acc[7] = __hfma2(qb.h[3], xr, acc[7]);                                 \
            acc[8] = __hfma2(qc.h[0], xr, acc[8]);                                 \
            acc[9] = __hfma2(qc.h[1], xr, acc[9]);                                 \
        }                                                                          \
    }

#define STASH(PVEC)                                                                \
    {                                                                              \
        F4H2 wa, wb; F2H2 wc;                                                      \
        _Pragma("unroll")                                                          \
        for (int h = 0; h < 4; h++) wa.h[h] = __float2half2_rn(PVEC[h]);           \
        _Pragma("unroll")                                                          \
        for (int h = 0; h < 4; h++) wb.h[h] = __float2half2_rn(PVEC[4 + h]);       \
        wc.h[0] = __float2half2_rn(PVEC[8]);                                       \
        wc.h[1] = __float2half2_rn(PVEC[9]);                                       \
        *(float4*)&pl[w][lane][0] = wa.f;                                          \
        *(float4*)&pl[w][lane][4] = wb.f;                                          \
        *(float2*)&pl[w][lane][8] = wc.f;                                          \
        sl[w][lane] = s;                                                           \
    }

    if (deg <= 64) {
        bool act = lane < deg;
        int s = act ? csrc[beg + lane] : 0;
        float p[10];
        if (act) {
            const float* sp = esg + (size_t)s * 16;
            float4 a = *(const float4*)sp, b = *(const float4*)(sp + 4);
            float2 c = *(const float2*)(sp + 8);
            float v[10];
            v[0] = a.x + edn[0]; v[1] = a.y + edn[1]; v[2] = a.z + edn[2]; v[3] = a.w + edn[3];
            v[4] = b.x + edn[4]; v[5] = b.y + edn[5]; v[6] = b.z + edn[6]; v[7] = b.w + edn[7];
            v[8] = c.x + edn[8]; v[9] = c.y + edn[9];
#pragma unroll
            for (int h = 0; h < 10; h++) {
                float vv = v[h] >= 0.f ? v[h] : 0.2f * v[h];
                p[h] = __expf(vv);
            }
        } else {
#pragma unroll
            for (int h = 0; h < 10; h++) p[h] = 0.f;
        }
        __half2 sh[5];
#pragma unroll
        for (int j = 0; j < 5; j++) sh[j] = __floats2half2_rn(p[2 * j], p[2 * j + 1]);
        int start = (deg <= 16) ? 8 : 32;
        for (int off = start; off; off >>= 1) {
#pragma unroll
            for (int j = 0; j < 5; j++) sh[j] = __hadd2(sh[j], shfl_xor_h2(sh[j], off));
        }
#pragma unroll
        for (int j = 0; j < 5; j++) {
            float2 f = __half22float2(sh[j]);
            p[2 * j] *= 1.f / f.x;
            p[2 * j + 1] *= 1.f / f.y;
        }
        STASH(p)
        PASSC_BODY(deg)
    } else {
        float ssf[10] = {};
        for (int cb = beg; cb < end; cb += 64) {
            int e = cb + lane;
            bool act = e < end;
            int si = act ? csrc[e] : 0;
            if (act) {
                const float* sp = esg + (size_t)si * 16;
#pragma unroll
                for (int h = 0; h < 10; h++) {
                    float vv = sp[h] + edn[h];
                    vv = vv >= 0.f ? vv : 0.2f * vv;
                    ssf[h] += __expf(vv);
                }
            }
        }
#pragma unroll
        for (int off = 32; off; off >>= 1) {
#pragma unroll
            for (int h = 0; h < 10; h++) ssf[h] += __shfl_xor(ssf[h], off);
        }
        float inv[10];
#pragma unroll
        for (int h = 0; h < 10; h++) inv[h] = 1.f / ssf[h];

        for (int cb = beg; cb < end; cb += 64) {
            int cnt = min(64, end - cb);
            int e = cb + lane;
            bool act = e < end;
            int s = act ? csrc[e] : 0;
            float p[10];
            if (act) {
                const float* sp = esg + (size_t)s * 16;
#pragma unroll
                for (int h = 0; h < 10; h++) {
                    float vv = sp[h] + edn[h];
                    vv = vv >= 0.f ? vv : 0.2f * vv;
                    p[h] = __expf(vv) * inv[h];
                }
            } else {
#pragma unroll
                for (int h = 0; h < 10; h++) p[h] = 0.f;
            }
            STASH(p)
            PASSC_BODY(cnt)
        }
    }
#undef PASSC_BODY
#undef STASH

    __half* op = xagg + (size_t)node * 800;
#pragma unroll
    for (int h = 0; h < 10; h++) {
        __half* hp = op + h * 80;
        hp[lane] = __low2half(acc[h]);
        if (lane < 16) hp[64 + lane] = __high2half(acc[h]);
    }
}

// ---------------- fused GEMM chain: 256 threads / 4 waves on the 16-row tile (r18 best) ----------------
__global__ __launch_bounds__(256) void k_gemmQ(const __half* __restrict__ xagg,
                                               const __half* __restrict__ W1T,
                                               const float* __restrict__ b1,
                                               const __half* __restrict__ W2T,
                                               const float* __restrict__ a2s,
                                               const float* __restrict__ a2d,
                                               __half* __restrict__ h216,
                                               float* __restrict__ es2,
                                               float* __restrict__ ed2, int N) {
    constexpr int LQ = 808;
    __shared__ __align__(16) _Float16 qlds[16 * LQ];  // 25.9 KB
    __shared__ float sered[4][2][16];
    int w = threadIdx.x >> 6, lane = threadIdx.x & 63;
    int row0 = blockIdx.x * 16;
    int col16 = lane & 15, grp = lane >> 4;
    int ko = grp * 8;
    int rbase = grp * 4;
    int ar = min(row0 + col16, N - 1);

    for (int i = threadIdx.x; i < 16 * 28; i += 256) {
        int r = i / 28, c = 780 + i % 28;
        qlds[r * LQ + c] = (_Float16)0.f;
    }

    // ---- phase 1: per-head 78->78 + bias + elu -> LDS ----
    const _Float16* Ab = (const _Float16*)xagg + (size_t)ar * 800 + ko;
    int h0 = (w < 2) ? w * 3 : 6 + (w - 2) * 2;
    int nh = (w < 2) ? 3 : 2;
    for (int hh = 0; hh < nh; hh++) {
        int h = h0 + hh;
        f4v acc1[5] = {};
        const _Float16* Ap = Ab + h * 80;
        const _Float16* Bp = (const _Float16*)W1T + ((size_t)h * 80 + col16) * 96 + ko;
#pragma unroll
        for (int ks = 0; ks < 3; ks++) {
            h8v a = *(const h8v*)(Ap + ks * 32);  // ks=2 overreads next head; W1T zeros cover
#pragma unroll
            for (int t = 0; t < 5; t++) {
                h8v b = *(const h8v*)(Bp + (size_t)t * 16 * 96 + ks * 32);
                acc1[t] = __builtin_amdgcn_mfma_f32_16x16x32_f16(a, b, acc1[t], 0, 0, 0);
            }
        }
#pragma unroll
        for (int t = 0; t < 5; t++) {
            int c = t * 16 + col16;
            if (c < 78) {
                float bias = b1[h * 78 + c];
#pragma unroll
                for (int r = 0; r < 4; r++) {
                    float v = acc1[t][r] + bias;
                    float e = v > 0.f ? v : (__expf(v) - 1.f);
                    qlds[(rbase + r) * LQ + h * 78 + c] = (_Float16)e;
                }
            }
        }
    }
    __syncthreads();

    // ---- phase 2: h216 = Q @ W2, t-tiles 2w..2w+1 ----
    f4v acc[2] = {};
    const _Float16* Bq = (const _Float16*)W2T + (size_t)col16 * 800 + ko;
    const _Float16* Aq = qlds + (size_t)col16 * LQ + ko;
    for (int ks = 0; ks < 25; ks++) {
        h8v a = *(const h8v*)(Aq + ks * 32);
#pragma unroll
        for (int t = 0; t < 2; t++) {
            h8v b = *(const h8v*)(Bq + (size_t)(w * 2 + t) * 16 * 800 + ks * 32);
            acc[t] = __builtin_amdgcn_mfma_f32_16x16x32_f16(a, b, acc[t], 0, 0, 0);
        }
    }
    float wa[2], wb[2];
#pragma unroll
    for (int t = 0; t < 2; t++) {
        wa[t] = a2s[(w * 2 + t) * 16 + col16];
        wb[t] = a2d[(w * 2 + t) * 16 + col16];
    }
#pragma unroll
    for (int r = 0; r < 4; r++) {
        int n = row0 + rbase + r;
        float se = 0.f, sd = 0.f;
#pragma unroll
        for (int t = 0; t < 2; t++) {
            float v = acc[t][r];
            se = fmaf(v, wa[t], se);
            sd = fmaf(v, wb[t], sd);
            if (n < N) h216[(size_t)n * 128 + (w * 2 + t) * 16 + col16] = __float2half(v);
        }
#pragma unroll
        for (int off = 1; off < 16; off <<= 1) {
            se += __shfl_xor(se, off);
            sd += __shfl_xor(sd, off);
        }
        if (col16 == 0) {
            sered[w][0][rbase + r] = se;
            sered[w][1][rbase + r] = sd;
        }
    }
    __syncthreads();
    if (threadIdx.x < 16) {
        int n = row0 + threadIdx.x;
        if (n < N) {
            es2[n] = sered[0][0][threadIdx.x] + sered[1][0][threadIdx.x] +
                     sered[2][0][threadIdx.x] + sered[3][0][threadIdx.x];
            ed2[n] = sered[0][1][threadIdx.x] + sered[1][1][threadIdx.x] +
                     sered[2][1][threadIdx.x] + sered[3][1][threadIdx.x];
        }
    }
}

// ---------------- layer-2 GAT + relu + block-pooled max -> gb ----------------
__global__ void k_gatP(const int* __restrict__ rp, const int* __restrict__ csrc,
                       const float* __restrict__ es, const float* __restrict__ ed,
                       const __half2* __restrict__ h216, const float* __restrict__ b2,
                       const int* __restrict__ batch, unsigned* __restrict__ gb, int N) {
    __shared__ float red[4][128];
    __shared__ int bids[4];
    __shared__ __align__(16) __half2 plP[4][64];
    __shared__ __align__(16) int slP[4][64];
    int w = threadIdx.x >> 6, lane = threadIdx.x & 63;
    int node = blockIdx.x * 4 + w;
    bool valid = node < N;

    __half2 acc = __floats2half2_rn(0.f, 0.f);
    int bid = -1;

#define PASSC2(LIMIT)                                                      \
    for (int i0 = 0; i0 < (LIMIT); i0 += 4) {                              \
        int4 s4 = *(const int4*)&slP[w][i0];                               \
        F4H2 q; q.f = *(const float4*)&plP[w][i0];                         \
        __half2 f0 = h216[(size_t)s4.x * 64 + lane];                       \
        __half2 f1 = h216[(size_t)s4.y * 64 + lane];                       \
        __half2 f2 = h216[(size_t)s4.z * 64 + lane];                       \
        __half2 f3 = h216[(size_t)s4.w * 64 + lane];                       \
        acc = __hfma2(q.h[0], f0, acc);                                    \
        acc = __hfma2(q.h[1], f1, acc);                                    \
        acc = __hfma2(q.h[2], f2, acc);                                    \
        acc = __hfma2(q.h[3], f3, acc);                                    \
    }

    if (valid) {
        int beg = rp[node], end = rp[node + 1];
        int deg = end - beg;
        float edn = ed[node];
        bid = batch[node];

        if (deg <= 64) {
            bool act = lane < deg;
            int s = act ? csrc[beg + lane] : 0;
            float p = 0.f;
            if (act) {
                float v = es[s] + edn;
                v = v >= 0.f ? v : 0.2f * v;
                p = __expf(v);
            }
            float ss = p;
            int start = (deg <= 16) ? 8 : 32;
            for (int off = start; off; off >>= 1) ss += __shfl_xor(ss, off);
            p *= 1.f / ss;
            plP[w][lane] = __float2half2_rn(p);
            slP[w][lane] = s;
            PASSC2(deg)
        } else {
            float ss = 0.f;
            for (int cb = beg; cb < end; cb += 64) {
                int e = cb + lane;
                bool act = e < end;
                int s = act ? csrc[e] : 0;
                if (act) {
                    float v = es[s] + edn;
                    v = v >= 0.f ? v : 0.2f * v;
                    ss += __expf(v);
                }
            }
#pragma unroll
            for (int off = 32; off; off >>= 1) ss += __shfl_xor(ss, off);
            float inv = 1.f / ss;
            for (int cb = beg; cb < end; cb += 64) {
                int cnt = min(64, end - cb);
                int e = cb + lane;
                bool act = e < end;
                int s = act ? csrc[e] : 0;
                float p = 0.f;
                if (act) {
                    float v = es[s] + edn;
                    v = v >= 0.f ? v : 0.2f * v;
                    p = __expf(v) * inv;
                }
                plP[w][lane] = __float2half2_rn(p);
                slP[w][lane] = s;
                PASSC2(cnt)
            }
        }
    }
#undef PASSC2

    float2 af = __half22float2(acc);
    red[w][2 * lane]     = valid ? fmaxf(af.x + b2[2 * lane], 0.f) : 0.f;
    red[w][2 * lane + 1] = valid ? fmaxf(af.y + b2[2 * lane + 1], 0.f) : 0.f;
    if (lane == 0) bids[w] = valid ? bid : -1;
    __syncthreads();
    if (threadIdx.x < 128) {
        int c = threadIdx.x;
        int b0 = bids[0];
        bool same = (bids[1] == b0) && (bids[2] == b0) && (bids[3] == b0);
        if (same && b0 >= 0) {
            float m = fmaxf(fmaxf(red[0][c], red[1][c]), fmaxf(red[2][c], red[3][c]));
            atomicMax(&gb[(size_t)b0 * 128 + c], __float_as_uint(m));
        } else {
#pragma unroll
            for (int w2 = 0; w2 < 4; w2++) {
                if (bids[w2] >= 0)
                    atomicMax(&gb[(size_t)bids[w2] * 128 + c], __float_as_uint(red[w2][c]));
            }
        }
    }
}

// ---------------- fused head part 1 ----------------
__global__ void k_head_gxt(const unsigned* __restrict__ gbits, const float* __restrict__ Wg,
                           const float* __restrict__ bg, const float* __restrict__ te,
                           const float* __restrict__ Wxt, const float* __restrict__ bxt,
                           const float* __restrict__ gamma, const float* __restrict__ beta,
                           const float* __restrict__ rmean, const float* __restrict__ rvar,
                           float* __restrict__ xc) {
    __shared__ float sg[F2];
    __shared__ float st[EMB];
    int b = blockIdx.x, t = threadIdx.x;
    if (t < 128) {
        sg[t] = __uint_as_float(gbits[(size_t)b * F2 + t]);
    } else {
        for (int k = t - 128; k < EMB; k += 128) st[k] = te[(size_t)b * EMB + k];
    }
    __syncthreads();
    if (t < 128) {
        float acc = bg[t];
        for (int k = 0; k < F2; k++) acc = fmaf(sg[k], Wg[k * F2 + t], acc);
        xc[(size_t)b * 256 + t] = fmaxf(acc, 0.f);
    } else {
        int c = t - 128;
        float acc = bxt[c];
        for (int k = 0; k < EMB; k++) acc = fmaf(st[k], Wxt[k * F2 + c], acc);
        acc = (acc - rmean[c]) * rsqrtf(rvar[c] + 1e-5f) * gamma[c] + beta[c];
        xc[(size_t)b * 256 + 128 + c] = fmaxf(acc, 0.f);
    }
}

// ---------------- fused head part 2 ----------------
__global__ void k_head_mlp(const float* __restrict__ xc, const float* __restrict__ Wf1,
                           const float* __restrict__ bf1, const float* __restrict__ Wf2,
                           const float* __restrict__ bf2, const float* __restrict__ Wo,
                           const float* __restrict__ bo, float* __restrict__ out) {
    __shared__ float s0[256];
    __shared__ float s1[1024];
    int b = blockIdx.x, t = threadIdx.x;
    s0[t] = xc[(size_t)b * 256 + t];
    __syncthreads();
    for (int col = t; col < 1024; col += 256) {
        float acc = bf1[col];
        for (int k = 0; k < 256; k++) acc = fmaf(s0[k], Wf1[k * 1024 + col], acc);
        s1[col] = fmaxf(acc, 0.f);
    }
    __syncthreads();
    {
        float acc = bf2[t];
        for (int k = 0; k < 1024; k++) acc = fmaf(s1[k], Wf2[k * 256 + t], acc);
        float v = fmaxf(acc, 0.f);
        __syncthreads();
        s0[t] = v * Wo[t];
    }
    __syncthreads();
    if (t < 64) {
        float acc = s0[t] + s0[64 + t] + s0[128 + t] + s0[192 + t];
        for (int off = 32; off; off >>= 1) acc += __shfl_down(acc, off);
        if (t == 0) out[b] = acc + bo[0];
    }
}

extern "C" void kernel_launch(void* const* d_in, const int* in_sizes, int n_in,
                              void* d_out, int out_size, void* d_ws, size_t ws_size,
                              hipStream_t stream) {
    const float* x     = (const float*)d_in[0];
    const int*   ei    = (const int*)d_in[1];
    const int*   batch = (const int*)d_in[2];
    const float* te    = (const float*)d_in[3];
    const float* W1    = (const float*)d_in[4];
    const float* a1s   = (const float*)d_in[5];
    const float* a1d   = (const float*)d_in[6];
    const float* b1    = (const float*)d_in[7];
    const float* W2    = (const float*)d_in[8];
    const float* a2s   = (const float*)d_in[9];
    const float* a2d   = (const float*)d_in[10];
    const float* b2    = (const float*)d_in[11];
    const float* Wg    = (const float*)d_in[12];
    const float* bg    = (const float*)d_in[13];
    const float* Wxt   = (const float*)d_in[14];
    const float* bxt   = (const float*)d_in[15];
    const float* gamma = (const float*)d_in[16];
    const float* beta  = (const float*)d_in[17];
    const float* rmean = (const float*)d_in[18];
    const float* rvar  = (const float*)d_in[19];
    const float* Wf1   = (const float*)d_in[20];
    const float* bf1   = (const float*)d_in[21];
    const float* Wf2   = (const float*)d_in[22];
    const float* bf2   = (const float*)d_in[23];
    const float* Wo    = (const float*)d_in[24];
    const float* bo    = (const float*)d_in[25];

    const int N = in_sizes[0] / 78;
    const int E = in_sizes[1] / 2;
    const int B = in_sizes[3] / EMB;
    const int Etot = E + N;
    const int* src = ei;
    const int* dst = ei + E;

    char* p = (char*)d_ws;
    auto alloc = [&](size_t bytes) -> void* {
        void* r = p;
        p += (bytes + 255) & ~(size_t)255;
        return r;
    };
    __half2*  xpk  = (__half2*)alloc((size_t)N * 64 * 4);
    __half*   xagg = (__half*)alloc((size_t)N * 800 * 2 + 256);
    __half*   h216 = (__half*)alloc((size_t)N * 128 * 2);
    float*    esg  = (float*)alloc((size_t)N * 16 * 4);
    float*    edg  = (float*)alloc((size_t)N * 16 * 4);
    float*    es2  = (float*)alloc((size_t)N * 4);
    float*    ed2  = (float*)alloc((size_t)N * 4);
    __half*   W1T  = (__half*)alloc((size_t)10 * 80 * 96 * 2);
    __half*   W2T  = (__half*)alloc((size_t)128 * 800 * 2);
    float*    wes  = (float*)alloc((size_t)800 * 4);
    float*    wed  = (float*)alloc((size_t)800 * 4);
    int*      cnt  = (int*)alloc((size_t)N * 4);
    int*      rp   = (int*)alloc((size_t)(N + 1) * 4);
    int*      cur  = (int*)alloc((size_t)N * 4);
    int*      csrc = (int*)alloc((size_t)Etot * 4);
    int*      bsum = (int*)alloc((size_t)1024 * 4);
    unsigned* gb   = (unsigned*)alloc((size_t)B * F2 * 4);
    float*    xc   = (float*)alloc((size_t)B * 256 * 4);

    auto gsz = [](long long t) { return (int)((t + 255) / 256); };
    const int nb = gsz(N);
    const int nwave = (N + 3) / 4;
    const int nrow16 = (N + 15) / 16;

    // ---- CSR build ----
    hipMemsetAsync(cnt, 0, (size_t)N * 4, stream);
    k_count<<<gsz(Etot), 256, 0, stream>>>(src, dst, E, Etot, cnt);
    k_scan1<<<nb, 256, 0, stream>>>(cnt, rp, bsum, N);
    k_scan2<<<1, 256, 0, stream>>>(bsum, nb);
    k_scan3<<<nb, 256, 0, stream>>>(rp, bsum, N, Etot, rp + N, cur);
    k_scatter<<<gsz(Etot), 256, 0, stream>>>(src, dst, E, Etot, cur, csrc);

    // ---- prep ----
    k_prep_w<<<gsz(77600 + 128 * 800), 256, 0, stream>>>(W1, a1s, a1d, W2, W1T, wes, wed, W2T);
    k_prep_xpk<<<gsz((long long)N * 64), 256, 0, stream>>>(x, xpk, N);
    k_coefx<<<nb, 256, 0, stream>>>(x, wes, wed, esg, edg, N);
    hipMemsetAsync(gb, 0, (size_t)B * F2 * 4, stream);

    // ---- GAT layer 1 (all 10 heads) ----
    k_gatx10<<<nwave, 256, 0, stream>>>(rp, csrc, esg, edg, xpk, xagg, N);

    // ---- fused GEMM chain (2-barrier, 256-thread blocks on 16-row tile) ----
    k_gemmQ<<<nrow16, 256, 0, stream>>>(xagg, W1T, b1, W2T, a2s, a2d, h216, es2, ed2, N);

    // ---- GAT layer 2 + fused pool ----
    k_gatP<<<nwave, 256, 0, stream>>>(rp, csrc, es2, ed2, (const __half2*)h216, b2, batch, gb, N);

    // ---- head (fused: 2 kernels) ----
    k_head_gxt<<<B, 256, 0, stream>>>(gb, Wg, bg, te, Wxt, bxt, gamma, beta, rmean, rvar, xc);
    k_head_mlp<<<B, 256, 0, stream>>>(xc, Wf1, bf1, Wf2, bf2, Wo, bo, (float*)d_out);
}

// Round 21
// 311.278 us; speedup vs baseline: 1.1513x; 1.0565x over previous
//
#include <hip/hip_runtime.h>
#include <hip/hip_fp16.h>
#include <math.h>

static constexpr int F2 = 128, EMB = 320;

typedef _Float16 h8v __attribute__((ext_vector_type(8)));
typedef float f4v __attribute__((ext_vector_type(4)));

union F4H2 { float4 f; __half2 h[4]; };
union F2H2 { float2 f; __half2 h[2]; };

__device__ __forceinline__ __half2 shfl_xor_h2(__half2 v, int off) {
    union { __half2 h; float f; } u;
    u.h = v;
    u.f = __shfl_xor(u.f, off);
    return u.h;
}

__device__ __forceinline__ void esd(const int* src, const int* dst, int E, int e, int& s, int& d) {
    if (e < E) { s = src[e]; d = dst[e]; }
    else       { s = e - E; d = s; }
}

// ---------------- CSR build ----------------
__global__ void k_count(const int* __restrict__ src, const int* __restrict__ dst, int E, int Etot,
                        int* __restrict__ cnt) {
    int e = blockIdx.x * 256 + threadIdx.x;
    if (e >= Etot) return;
    int s, d;
    esd(src, dst, E, e, s, d);
    atomicAdd(&cnt[d], 1);
}

__global__ void k_scan1(const int* __restrict__ in, int* __restrict__ out, int* __restrict__ bsum,
                        int n) {
    __shared__ int tmp[256];
    int t = threadIdx.x;
    int gid = blockIdx.x * 256 + t;
    int v = gid < n ? in[gid] : 0;
    tmp[t] = v;
    __syncthreads();
    for (int off = 1; off < 256; off <<= 1) {
        int u = (t >= off) ? tmp[t - off] : 0;
        __syncthreads();
        tmp[t] += u;
        __syncthreads();
    }
    if (gid < n) out[gid] = tmp[t] - v;
    if (t == 255) bsum[blockIdx.x] = tmp[255];
}

__global__ void k_scan2(int* __restrict__ bsum, int nb) {
    __shared__ int tmp[256];
    __shared__ int carry;
    int t = threadIdx.x;
    if (t == 0) carry = 0;
    __syncthreads();
    for (int base = 0; base < nb; base += 256) {
        int i = base + t;
        int v = (i < nb) ? bsum[i] : 0;
        tmp[t] = v;
        __syncthreads();
        for (int off = 1; off < 256; off <<= 1) {
            int u = (t >= off) ? tmp[t - off] : 0;
            __syncthreads();
            tmp[t] += u;
            __syncthreads();
        }
        if (i < nb) bsum[i] = tmp[t] - v + carry;
        __syncthreads();
        if (t == 0) carry += tmp[255];
        __syncthreads();
    }
}

__global__ void k_scan3(int* __restrict__ out, const int* __restrict__ bsum, int n, int Etot,
                        int* __restrict__ rp_last, int* __restrict__ cur) {
    int gid = blockIdx.x * 256 + threadIdx.x;
    if (gid < n) {
        int v = out[gid] + bsum[blockIdx.x];
        out[gid] = v;
        cur[gid] = v;
    }
    if (gid == 0) rp_last[0] = Etot;
}

__global__ void k_scatter(const int* __restrict__ src, const int* __restrict__ dst, int E, int Etot,
                          int* __restrict__ cur, int* __restrict__ csrc) {
    int e = blockIdx.x * 256 + threadIdx.x;
    if (e >= Etot) return;
    int s, d;
    esd(src, dst, E, e, s, d);
    int pos = atomicAdd(&cur[d], 1);
    csrc[pos] = s;
}

// ---------------- merged weight prep ----------------
__global__ void k_prep_w(const float* __restrict__ W1, const float* __restrict__ a1s,
                         const float* __restrict__ a1d, const float* __restrict__ W2,
                         __half* __restrict__ W1T, float* __restrict__ wes,
                         float* __restrict__ wed, __half* __restrict__ W2T) {
    int idx = blockIdx.x * 256 + threadIdx.x;
    if (idx < 76800) {
        int h = idx / (80 * 96), r = idx % (80 * 96), c = r / 96, k = r % 96;
        float v = (c < 78 && k < 78) ? W1[(size_t)k * 780 + h * 78 + c] : 0.f;
        W1T[idx] = __float2half(v);
    } else if (idx < 77600) {
        int j = idx - 76800;
        int h = j / 80, k = j % 80;
        float s = 0.f, d = 0.f;
        if (k < 78) {
            for (int f = 0; f < 78; f++) {
                float w = W1[(size_t)k * 780 + h * 78 + f];
                s = fmaf(w, a1s[h * 78 + f], s);
                d = fmaf(w, a1d[h * 78 + f], d);
            }
        }
        wes[j] = s;
        wed[j] = d;
    } else if (idx < 77600 + 128 * 800) {
        int j = idx - 77600;
        int c = j / 800, k = j % 800;
        float v = (k < 780) ? W2[(size_t)k * 128 + c] : 0.f;
        W2T[j] = __float2half(v);
    }
}

// xpk [N][64] half2: {x[c], x[c+64] or 0}
__global__ void k_prep_xpk(const float* __restrict__ x, __half2* __restrict__ xpk, int N) {
    int idx = blockIdx.x * 256 + threadIdx.x;
    if (idx >= N * 64) return;
    int n = idx >> 6, l = idx & 63;
    float lo = x[(size_t)n * 78 + l];
    float hi = (64 + l < 78) ? x[(size_t)n * 78 + 64 + l] : 0.f;
    xpk[idx] = __floats2half2_rn(lo, hi);
}

// es/ed for all 10 heads: esg/edg [N][16]
__global__ void k_coefx(const float* __restrict__ x, const float* __restrict__ wes,
                        const float* __restrict__ wed, float* __restrict__ esg,
                        float* __restrict__ edg, int N) {
    int n = blockIdx.x * 256 + threadIdx.x;
    if (n >= N) return;
    float es[10] = {}, ed[10] = {};
    const float* xr = x + (size_t)n * 78;
    for (int k = 0; k < 78; k++) {
        float xv = xr[k];
#pragma unroll
        for (int h = 0; h < 10; h++) {
            es[h] = fmaf(xv, wes[h * 80 + k], es[h]);
            ed[h] = fmaf(xv, wed[h * 80 + k], ed[h]);
        }
    }
#pragma unroll
    for (int h = 0; h < 10; h++) {
        esg[(size_t)n * 16 + h] = es[h];
        edg[(size_t)n * 16 + h] = ed[h];
    }
}

// ---------------- fused 10-head GAT on x -> xagg [N][10][80] fp16 ----------------
__global__ void k_gatx10(const int* __restrict__ rp, const int* __restrict__ csrc,
                         const float* __restrict__ esg, const float* __restrict__ edg,
                         const __half2* __restrict__ xpk, __half* __restrict__ xagg, int N) {
    __shared__ __align__(16) __half2 pl[4][64][12];
    __shared__ __align__(16) int sl[4][64];
    int w = threadIdx.x >> 6, lane = threadIdx.x & 63;
    int node = blockIdx.x * 4 + w;
    if (node >= N) return;
    int beg = rp[node], end = rp[node + 1];
    int deg = end - beg;

    float edn[10];
    {
        const float* ep = edg + (size_t)node * 16;
        float4 a = *(const float4*)ep, b = *(const float4*)(ep + 4);
        float2 c = *(const float2*)(ep + 8);
        edn[0] = a.x; edn[1] = a.y; edn[2] = a.z; edn[3] = a.w;
        edn[4] = b.x; edn[5] = b.y; edn[6] = b.z; edn[7] = b.w;
        edn[8] = c.x; edn[9] = c.y;
    }

    __half2 acc[10];
#pragma unroll
    for (int h = 0; h < 10; h++) acc[h] = __floats2half2_rn(0.f, 0.f);

#define PASSC_BODY(LIMIT)                                                          \
    for (int i0 = 0; i0 < (LIMIT); i0 += 4) {                                      \
        int4 s4 = *(const int4*)&sl[w][i0];                                        \
        __half2 xr0 = xpk[(size_t)s4.x * 64 + lane];                               \
        __half2 xr1 = xpk[(size_t)s4.y * 64 + lane];                               \
        __half2 xr2 = xpk[(size_t)s4.z * 64 + lane];                               \
        __half2 xr3 = xpk[(size_t)s4.w * 64 + lane];                               \
        _Pragma("unroll")                                                          \
        for (int j = 0; j < 4; j++) {                                              \
            F4H2 qa, qb; F2H2 qc;                                                  \
            qa.f = *(const float4*)&pl[w][i0 + j][0];                              \
            qb.f = *(const float4*)&pl[w][i0 + j][4];                              \
            qc.f = *(const float2*)&pl[w][i0 + j][8];                              \
            __half2 xr = (j == 0) ? xr0 : (j == 1) ? xr1 : (j == 2) ? xr2 : xr3;   \
            acc[0] = __hfma2(qa.h[0], xr, acc[0]);                                 \
            acc[1] = __hfma2(qa.h[1], xr, acc[1]);                                 \
            acc[2] = __hfma2(qa.h[2], xr, acc[2]);                                 \
            acc[3] = __hfma2(qa.h[3], xr, acc[3]);                                 \
            acc[4] = __hfma2(qb.h[0], xr, acc[4]);                                 \
            acc[5] = __hfma2(qb.h[1], xr, acc[5]);                                 \
            acc[6] = __hfma2(qb.h[2], xr, acc[6]);                                 \
            acc[7] = __hfma2(qb.h[3], xr, acc[7]);                                 \
            acc[8] = __hfma2(qc.h[0], xr, acc[8]);                                 \
            acc[9] = __hfma2(qc.h[1], xr, acc[9]);                                 \
        }                                                                          \
    }

#define STASH(PVEC)                                                                \
    {                                                                              \
        F4H2 wa, wb; F2H2 wc;                                                      \
        _Pragma("unroll")                                                          \
        for (int h = 0; h < 4; h++) wa.h[h] = __float2half2_rn(PVEC[h]);           \
        _Pragma("unroll")                                                          \
        for (int h = 0; h < 4; h++) wb.h[h] = __float2half2_rn(PVEC[4 + h]);       \
        wc.h[0] = __float2half2_rn(PVEC[8]);                                       \
        wc.h[1] = __float2half2_rn(PVEC[9]);                                       \
        *(float4*)&pl[w][lane][0] = wa.f;                                          \
        *(float4*)&pl[w][lane][4] = wb.f;                                          \
        *(float2*)&pl[w][lane][8] = wc.f;                                          \
        sl[w][lane] = s;                                                           \
    }

    if (deg <= 64) {
        bool act = lane < deg;
        int s = act ? csrc[beg + lane] : 0;
        float p[10];
        if (act) {
            const float* sp = esg + (size_t)s * 16;
            float4 a = *(const float4*)sp, b = *(const float4*)(sp + 4);
            float2 c = *(const float2*)(sp + 8);
            float v[10];
            v[0] = a.x + edn[0]; v[1] = a.y + edn[1]; v[2] = a.z + edn[2]; v[3] = a.w + edn[3];
            v[4] = b.x + edn[4]; v[5] = b.y + edn[5]; v[6] = b.z + edn[6]; v[7] = b.w + edn[7];
            v[8] = c.x + edn[8]; v[9] = c.y + edn[9];
#pragma unroll
            for (int h = 0; h < 10; h++) {
                float vv = v[h] >= 0.f ? v[h] : 0.2f * v[h];
                p[h] = __expf(vv);
            }
        } else {
#pragma unroll
            for (int h = 0; h < 10; h++) p[h] = 0.f;
        }
        __half2 sh[5];
#pragma unroll
        for (int j = 0; j < 5; j++) sh[j] = __floats2half2_rn(p[2 * j], p[2 * j + 1]);
        int start = (deg <= 16) ? 8 : 32;
        for (int off = start; off; off >>= 1) {
#pragma unroll
            for (int j = 0; j < 5; j++) sh[j] = __hadd2(sh[j], shfl_xor_h2(sh[j], off));
        }
#pragma unroll
        for (int j = 0; j < 5; j++) {
            float2 f = __half22float2(sh[j]);
            p[2 * j] *= 1.f / f.x;
            p[2 * j + 1] *= 1.f / f.y;
        }
        STASH(p)
        PASSC_BODY(deg)
    } else {
        float ssf[10] = {};
        for (int cb = beg; cb < end; cb += 64) {
            int e = cb + lane;
            bool act = e < end;
            int si = act ? csrc[e] : 0;
            if (act) {
                const float* sp = esg + (size_t)si * 16;
#pragma unroll
                for (int h = 0; h < 10; h++) {
                    float vv = sp[h] + edn[h];
                    vv = vv >= 0.f ? vv : 0.2f * vv;
                    ssf[h] += __expf(vv);
                }
            }
        }
#pragma unroll
        for (int off = 32; off; off >>= 1) {
#pragma unroll
            for (int h = 0; h < 10; h++) ssf[h] += __shfl_xor(ssf[h], off);
        }
        float inv[10];
#pragma unroll
        for (int h = 0; h < 10; h++) inv[h] = 1.f / ssf[h];

        for (int cb = beg; cb < end; cb += 64) {
            int cnt = min(64, end - cb);
            int e = cb + lane;
            bool act = e < end;
            int s = act ? csrc[e] : 0;
            float p[10];
            if (act) {
                const float* sp = esg + (size_t)s * 16;
#pragma unroll
                for (int h = 0; h < 10; h++) {
                    float vv = sp[h] + edn[h];
                    vv = vv >= 0.f ? vv : 0.2f * vv;
                    p[h] = __expf(vv) * inv[h];
                }
            } else {
#pragma unroll
                for (int h = 0; h < 10; h++) p[h] = 0.f;
            }
            STASH(p)
            PASSC_BODY(cnt)
        }
    }
#undef PASSC_BODY
#undef STASH

    __half* op = xagg + (size_t)node * 800;
#pragma unroll
    for (int h = 0; h < 10; h++) {
        __half* hp = op + h * 80;
        hp[lane] = __low2half(acc[h]);
        if (lane < 16) hp[64 + lane] = __high2half(acc[h]);
    }
}

// ---------------- fused GEMM chain: 32 rows / 512 thr / 8 waves (B reused across 2 row-blocks) ----
// Phase 1: 20 head-jobs (head x row-half) over 8 waves. Phase 2: wave w owns t-tile w over both
// 16-row blocks (one B-load feeds 2 MFMA). es/ed scratch aliases dead qlds after a barrier.
__global__ __launch_bounds__(512) void k_gemmQ(const __half* __restrict__ xagg,
                                               const __half* __restrict__ W1T,
                                               const float* __restrict__ b1,
                                               const __half* __restrict__ W2T,
                                               const float* __restrict__ a2s,
                                               const float* __restrict__ a2d,
                                               __half* __restrict__ h216,
                                               float* __restrict__ es2,
                                               float* __restrict__ ed2, int N) {
    constexpr int LQ = 808;
    __shared__ __align__(16) _Float16 qlds[32 * LQ];  // 50.5 KB; front 2 KB reused as sered later
    int w = threadIdx.x >> 6, lane = threadIdx.x & 63;
    int row0 = blockIdx.x * 32;
    int col16 = lane & 15, grp = lane >> 4;
    int ko = grp * 8;
    int rbase = grp * 4;

    // zero pad cols 780..807 for all 32 rows
    for (int i = threadIdx.x; i < 32 * 28; i += 512) {
        int r = i / 28, c = 780 + i % 28;
        qlds[r * LQ + c] = (_Float16)0.f;
    }

    // ---- phase 1: job j -> head j>>1, row-half j&1 ----
    for (int j = w; j < 20; j += 8) {
        int h = j >> 1, half = j & 1;
        int ar = min(row0 + half * 16 + col16, N - 1);
        const _Float16* Ap = (const _Float16*)xagg + (size_t)ar * 800 + h * 80 + ko;
        const _Float16* Bp = (const _Float16*)W1T + ((size_t)h * 80 + col16) * 96 + ko;
        f4v acc1[5] = {};
#pragma unroll
        for (int ks = 0; ks < 3; ks++) {
            h8v a = *(const h8v*)(Ap + ks * 32);  // ks=2 overreads next head; W1T zeros cover
#pragma unroll
            for (int t = 0; t < 5; t++) {
                h8v b = *(const h8v*)(Bp + (size_t)t * 16 * 96 + ks * 32);
                acc1[t] = __builtin_amdgcn_mfma_f32_16x16x32_f16(a, b, acc1[t], 0, 0, 0);
            }
        }
#pragma unroll
        for (int t = 0; t < 5; t++) {
            int c = t * 16 + col16;
            if (c < 78) {
                float bias = b1[h * 78 + c];
#pragma unroll
                for (int r = 0; r < 4; r++) {
                    float v = acc1[t][r] + bias;
                    float e = v > 0.f ? v : (__expf(v) - 1.f);
                    qlds[(half * 16 + rbase + r) * LQ + h * 78 + c] = (_Float16)e;
                }
            }
        }
    }
    __syncthreads();

    // ---- phase 2: wave w -> t-tile w over both row-blocks ----
    f4v acc0 = {}, acc1 = {};
    const _Float16* Bq = (const _Float16*)W2T + ((size_t)w * 16 + col16) * 800 + ko;
    const _Float16* Aq0 = qlds + (size_t)col16 * LQ + ko;
    const _Float16* Aq1 = qlds + (size_t)(16 + col16) * LQ + ko;
    for (int ks = 0; ks < 25; ks++) {
        h8v b = *(const h8v*)(Bq + ks * 32);
        h8v a0 = *(const h8v*)(Aq0 + ks * 32);
        h8v a1 = *(const h8v*)(Aq1 + ks * 32);
        acc0 = __builtin_amdgcn_mfma_f32_16x16x32_f16(a0, b, acc0, 0, 0, 0);
        acc1 = __builtin_amdgcn_mfma_f32_16x16x32_f16(a1, b, acc1, 0, 0, 0);
    }
    float wa = a2s[w * 16 + col16], wb = a2d[w * 16 + col16];
    float sse[2][4], ssd[2][4];
#pragma unroll
    for (int rb = 0; rb < 2; rb++) {
#pragma unroll
        for (int r = 0; r < 4; r++) {
            int n = row0 + rb * 16 + rbase + r;
            float v = rb ? acc1[r] : acc0[r];
            float se = v * wa, sd = v * wb;
#pragma unroll
            for (int off = 1; off < 16; off <<= 1) {
                se += __shfl_xor(se, off);
                sd += __shfl_xor(sd, off);
            }
            sse[rb][r] = se;
            ssd[rb][r] = sd;
            if (n < N) h216[(size_t)n * 128 + w * 16 + col16] = __float2half(v);
        }
    }
    __syncthreads();  // all qlds reads done -> safe to alias front as sered[8][2][32]
    float* seredf = (float*)qlds;
    if (col16 == 0) {
#pragma unroll
        for (int rb = 0; rb < 2; rb++) {
#pragma unroll
            for (int r = 0; r < 4; r++) {
                int rowi = rb * 16 + rbase + r;
                seredf[w * 64 + rowi] = sse[rb][r];
                seredf[w * 64 + 32 + rowi] = ssd[rb][r];
            }
        }
    }
    __syncthreads();
    if (threadIdx.x < 32) {
        int n = row0 + threadIdx.x;
        if (n < N) {
            float es = 0.f, ed = 0.f;
#pragma unroll
            for (int ww = 0; ww < 8; ww++) {
                es += seredf[ww * 64 + threadIdx.x];
                ed += seredf[ww * 64 + 32 + threadIdx.x];
            }
            es2[n] = es;
            ed2[n] = ed;
        }
    }
}

// ---------------- layer-2 GAT + relu + block-pooled max -> gb ----------------
__global__ void k_gatP(const int* __restrict__ rp, const int* __restrict__ csrc,
                       const float* __restrict__ es, const float* __restrict__ ed,
                       const __half2* __restrict__ h216, const float* __restrict__ b2,
                       const int* __restrict__ batch, unsigned* __restrict__ gb, int N) {
    __shared__ float red[4][128];
    __shared__ int bids[4];
    __shared__ __align__(16) __half2 plP[4][64];
    __shared__ __align__(16) int slP[4][64];
    int w = threadIdx.x >> 6, lane = threadIdx.x & 63;
    int node = blockIdx.x * 4 + w;
    bool valid = node < N;

    __half2 acc = __floats2half2_rn(0.f, 0.f);
    int bid = -1;

#define PASSC2(LIMIT)                                                      \
    for (int i0 = 0; i0 < (LIMIT); i0 += 4) {                              \
        int4 s4 = *(const int4*)&slP[w][i0];                               \
        F4H2 q; q.f = *(const float4*)&plP[w][i0];                         \
        __half2 f0 = h216[(size_t)s4.x * 64 + lane];                       \
        __half2 f1 = h216[(size_t)s4.y * 64 + lane];                       \
        __half2 f2 = h216[(size_t)s4.z * 64 + lane];                       \
        __half2 f3 = h216[(size_t)s4.w * 64 + lane];                       \
        acc = __hfma2(q.h[0], f0, acc);                                    \
        acc = __hfma2(q.h[1], f1, acc);                                    \
        acc = __hfma2(q.h[2], f2, acc);                                    \
        acc = __hfma2(q.h[3], f3, acc);                                    \
    }

    if (valid) {
        int beg = rp[node], end = rp[node + 1];
        int deg = end - beg;
        float edn = ed[node];
        bid = batch[node];

        if (deg <= 64) {
            bool act = lane < deg;
            int s = act ? csrc[beg + lane] : 0;
            float p = 0.f;
            if (act) {
                float v = es[s] + edn;
                v = v >= 0.f ? v : 0.2f * v;
                p = __expf(v);
            }
            float ss = p;
            int start = (deg <= 16) ? 8 : 32;
            for (int off = start; off; off >>= 1) ss += __shfl_xor(ss, off);
            p *= 1.f / ss;
            plP[w][lane] = __float2half2_rn(p);
            slP[w][lane] = s;
            PASSC2(deg)
        } else {
            float ss = 0.f;
            for (int cb = beg; cb < end; cb += 64) {
                int e = cb + lane;
                bool act = e < end;
                int s = act ? csrc[e] : 0;
                if (act) {
                    float v = es[s] + edn;
                    v = v >= 0.f ? v : 0.2f * v;
                    ss += __expf(v);
                }
            }
#pragma unroll
            for (int off = 32; off; off >>= 1) ss += __shfl_xor(ss, off);
            float inv = 1.f / ss;
            for (int cb = beg; cb < end; cb += 64) {
                int cnt = min(64, end - cb);
                int e = cb + lane;
                bool act = e < end;
                int s = act ? csrc[e] : 0;
                float p = 0.f;
                if (act) {
                    float v = es[s] + edn;
                    v = v >= 0.f ? v : 0.2f * v;
                    p = __expf(v) * inv;
                }
                plP[w][lane] = __float2half2_rn(p);
                slP[w][lane] = s;
                PASSC2(cnt)
            }
        }
    }
#undef PASSC2

    float2 af = __half22float2(acc);
    red[w][2 * lane]     = valid ? fmaxf(af.x + b2[2 * lane], 0.f) : 0.f;
    red[w][2 * lane + 1] = valid ? fmaxf(af.y + b2[2 * lane + 1], 0.f) : 0.f;
    if (lane == 0) bids[w] = valid ? bid : -1;
    __syncthreads();
    if (threadIdx.x < 128) {
        int c = threadIdx.x;
        int b0 = bids[0];
        bool same = (bids[1] == b0) && (bids[2] == b0) && (bids[3] == b0);
        if (same && b0 >= 0) {
            float m = fmaxf(fmaxf(red[0][c], red[1][c]), fmaxf(red[2][c], red[3][c]));
            atomicMax(&gb[(size_t)b0 * 128 + c], __float_as_uint(m));
        } else {
#pragma unroll
            for (int w2 = 0; w2 < 4; w2++) {
                if (bids[w2] >= 0)
                    atomicMax(&gb[(size_t)bids[w2] * 128 + c], __float_as_uint(red[w2][c]));
            }
        }
    }
}

// ---------------- fused head part 1 ----------------
__global__ void k_head_gxt(const unsigned* __restrict__ gbits, const float* __restrict__ Wg,
                           const float* __restrict__ bg, const float* __restrict__ te,
                           const float* __restrict__ Wxt, const float* __restrict__ bxt,
                           const float* __restrict__ gamma, const float* __restrict__ beta,
                           const float* __restrict__ rmean, const float* __restrict__ rvar,
                           float* __restrict__ xc) {
    __shared__ float sg[F2];
    __shared__ float st[EMB];
    int b = blockIdx.x, t = threadIdx.x;
    if (t < 128) {
        sg[t] = __uint_as_float(gbits[(size_t)b * F2 + t]);
    } else {
        for (int k = t - 128; k < EMB; k += 128) st[k] = te[(size_t)b * EMB + k];
    }
    __syncthreads();
    if (t < 128) {
        float acc = bg[t];
        for (int k = 0; k < F2; k++) acc = fmaf(sg[k], Wg[k * F2 + t], acc);
        xc[(size_t)b * 256 + t] = fmaxf(acc, 0.f);
    } else {
        int c = t - 128;
        float acc = bxt[c];
        for (int k = 0; k < EMB; k++) acc = fmaf(st[k], Wxt[k * F2 + c], acc);
        acc = (acc - rmean[c]) * rsqrtf(rvar[c] + 1e-5f) * gamma[c] + beta[c];
        xc[(size_t)b * 256 + 128 + c] = fmaxf(acc, 0.f);
    }
}

// ---------------- fused head part 2 ----------------
__global__ void k_head_mlp(const float* __restrict__ xc, const float* __restrict__ Wf1,
                           const float* __restrict__ bf1, const float* __restrict__ Wf2,
                           const float* __restrict__ bf2, const float* __restrict__ Wo,
                           const float* __restrict__ bo, float* __restrict__ out) {
    __shared__ float s0[256];
    __shared__ float s1[1024];
    int b = blockIdx.x, t = threadIdx.x;
    s0[t] = xc[(size_t)b * 256 + t];
    __syncthreads();
    for (int col = t; col < 1024; col += 256) {
        float acc = bf1[col];
        for (int k = 0; k < 256; k++) acc = fmaf(s0[k], Wf1[k * 1024 + col], acc);
        s1[col] = fmaxf(acc, 0.f);
    }
    __syncthreads();
    {
        float acc = bf2[t];
        for (int k = 0; k < 1024; k++) acc = fmaf(s1[k], Wf2[k * 256 + t], acc);
        float v = fmaxf(acc, 0.f);
        __syncthreads();
        s0[t] = v * Wo[t];
    }
    __syncthreads();
    if (t < 64) {
        float acc = s0[t] + s0[64 + t] + s0[128 + t] + s0[192 + t];
        for (int off = 32; off; off >>= 1) acc += __shfl_down(acc, off);
        if (t == 0) out[b] = acc + bo[0];
    }
}

extern "C" void kernel_launch(void* const* d_in, const int* in_sizes, int n_in,
                              void* d_out, int out_size, void* d_ws, size_t ws_size,
                              hipStream_t stream) {
    const float* x     = (const float*)d_in[0];
    const int*   ei    = (const int*)d_in[1];
    const int*   batch = (const int*)d_in[2];
    const float* te    = (const float*)d_in[3];
    const float* W1    = (const float*)d_in[4];
    const float* a1s   = (const float*)d_in[5];
    const float* a1d   = (const float*)d_in[6];
    const float* b1    = (const float*)d_in[7];
    const float* W2    = (const float*)d_in[8];
    const float* a2s   = (const float*)d_in[9];
    const float* a2d   = (const float*)d_in[10];
    const float* b2    = (const float*)d_in[11];
    const float* Wg    = (const float*)d_in[12];
    const float* bg    = (const float*)d_in[13];
    const float* Wxt   = (const float*)d_in[14];
    const float* bxt   = (const float*)d_in[15];
    const float* gamma = (const float*)d_in[16];
    const float* beta  = (const float*)d_in[17];
    const float* rmean = (const float*)d_in[18];
    const float* rvar  = (const float*)d_in[19];
    const float* Wf1   = (const float*)d_in[20];
    const float* bf1   = (const float*)d_in[21];
    const float* Wf2   = (const float*)d_in[22];
    const float* bf2   = (const float*)d_in[23];
    const float* Wo    = (const float*)d_in[24];
    const float* bo    = (const float*)d_in[25];

    const int N = in_sizes[0] / 78;
    const int E = in_sizes[1] / 2;
    const int B = in_sizes[3] / EMB;
    const int Etot = E + N;
    const int* src = ei;
    const int* dst = ei + E;

    char* p = (char*)d_ws;
    auto alloc = [&](size_t bytes) -> void* {
        void* r = p;
        p += (bytes + 255) & ~(size_t)255;
        return r;
    };
    __half2*  xpk  = (__half2*)alloc((size_t)N * 64 * 4);
    __half*   xagg = (__half*)alloc((size_t)N * 800 * 2 + 256);
    __half*   h216 = (__half*)alloc((size_t)N * 128 * 2);
    float*    esg  = (float*)alloc((size_t)N * 16 * 4);
    float*    edg  = (float*)alloc((size_t)N * 16 * 4);
    float*    es2  = (float*)alloc((size_t)N * 4);
    float*    ed2  = (float*)alloc((size_t)N * 4);
    __half*   W1T  = (__half*)alloc((size_t)10 * 80 * 96 * 2);
    __half*   W2T  = (__half*)alloc((size_t)128 * 800 * 2);
    float*    wes  = (float*)alloc((size_t)800 * 4);
    float*    wed  = (float*)alloc((size_t)800 * 4);
    int*      cnt  = (int*)alloc((size_t)N * 4);
    int*      rp   = (int*)alloc((size_t)(N + 1) * 4);
    int*      cur  = (int*)alloc((size_t)N * 4);
    int*      csrc = (int*)alloc((size_t)Etot * 4);
    int*      bsum = (int*)alloc((size_t)1024 * 4);
    unsigned* gb   = (unsigned*)alloc((size_t)B * F2 * 4);
    float*    xc   = (float*)alloc((size_t)B * 256 * 4);

    auto gsz = [](long long t) { return (int)((t + 255) / 256); };
    const int nb = gsz(N);
    const int nwave = (N + 3) / 4;
    const int nrow32 = (N + 31) / 32;

    // ---- CSR build ----
    hipMemsetAsync(cnt, 0, (size_t)N * 4, stream);
    k_count<<<gsz(Etot), 256, 0, stream>>>(src, dst, E, Etot, cnt);
    k_scan1<<<nb, 256, 0, stream>>>(cnt, rp, bsum, N);
    k_scan2<<<1, 256, 0, stream>>>(bsum, nb);
    k_scan3<<<nb, 256, 0, stream>>>(rp, bsum, N, Etot, rp + N, cur);
    k_scatter<<<gsz(Etot), 256, 0, stream>>>(src, dst, E, Etot, cur, csrc);

    // ---- prep ----
    k_prep_w<<<gsz(77600 + 128 * 800), 256, 0, stream>>>(W1, a1s, a1d, W2, W1T, wes, wed, W2T);
    k_prep_xpk<<<gsz((long long)N * 64), 256, 0, stream>>>(x, xpk, N);
    k_coefx<<<nb, 256, 0, stream>>>(x, wes, wed, esg, edg, N);
    hipMemsetAsync(gb, 0, (size_t)B * F2 * 4, stream);

    // ---- GAT layer 1 (all 10 heads) ----
    k_gatx10<<<nwave, 256, 0, stream>>>(rp, csrc, esg, edg, xpk, xagg, N);

    // ---- fused GEMM chain (32-row / 512-thread blocks, B reused across row-blocks) ----
    k_gemmQ<<<nrow32, 512, 0, stream>>>(xagg, W1T, b1, W2T, a2s, a2d, h216, es2, ed2, N);

    // ---- GAT layer 2 + fused pool ----
    k_gatP<<<nwave, 256, 0, stream>>>(rp, csrc, es2, ed2, (const __half2*)h216, b2, batch, gb, N);

    // ---- head (fused: 2 kernels) ----
    k_head_gxt<<<B, 256, 0, stream>>>(gb, Wg, bg, te, Wxt, bxt, gamma, beta, rmean, rvar, xc);
    k_head_mlp<<<B, 256, 0, stream>>>(xc, Wf1, bf1, Wf2, bf2, Wo, bo, (float*)d_out);
}

// Round 22
// 294.576 us; speedup vs baseline: 1.2165x; 1.0567x over previous
//
#include <hip/hip_runtime.h>
#include <hip/hip_fp16.h>
#include <math.h>

static constexpr int F2 = 128, EMB = 320;

typedef _Float16 h8v __attribute__((ext_vector_type(8)));
typedef float f4v __attribute__((ext_vector_type(4)));

union F4H2 { float4 f; __half2 h[4]; };
union F2H2 { float2 f; __half2 h[2]; };

__device__ __forceinline__ __half2 shfl_xor_h2(__half2 v, int off) {
    union { __half2 h; float f; } u;
    u.h = v;
    u.f = __shfl_xor(u.f, off);
    return u.h;
}

__device__ __forceinline__ void esd(const int* src, const int* dst, int E, int e, int& s, int& d) {
    if (e < E) { s = src[e]; d = dst[e]; }
    else       { s = e - E; d = s; }
}

// ---------------- CSR build ----------------
__global__ void k_count(const int* __restrict__ src, const int* __restrict__ dst, int E, int Etot,
                        int* __restrict__ cnt) {
    int e = blockIdx.x * 256 + threadIdx.x;
    if (e >= Etot) return;
    int s, d;
    esd(src, dst, E, e, s, d);
    atomicAdd(&cnt[d], 1);
}

__global__ void k_scan1(const int* __restrict__ in, int* __restrict__ out, int* __restrict__ bsum,
                        int n) {
    __shared__ int tmp[256];
    int t = threadIdx.x;
    int gid = blockIdx.x * 256 + t;
    int v = gid < n ? in[gid] : 0;
    tmp[t] = v;
    __syncthreads();
    for (int off = 1; off < 256; off <<= 1) {
        int u = (t >= off) ? tmp[t - off] : 0;
        __syncthreads();
        tmp[t] += u;
        __syncthreads();
    }
    if (gid < n) out[gid] = tmp[t] - v;
    if (t == 255) bsum[blockIdx.x] = tmp[255];
}

__global__ void k_scan2(int* __restrict__ bsum, int nb) {
    __shared__ int tmp[256];
    __shared__ int carry;
    int t = threadIdx.x;
    if (t == 0) carry = 0;
    __syncthreads();
    for (int base = 0; base < nb; base += 256) {
        int i = base + t;
        int v = (i < nb) ? bsum[i] : 0;
        tmp[t] = v;
        __syncthreads();
        for (int off = 1; off < 256; off <<= 1) {
            int u = (t >= off) ? tmp[t - off] : 0;
            __syncthreads();
            tmp[t] += u;
            __syncthreads();
        }
        if (i < nb) bsum[i] = tmp[t] - v + carry;
        __syncthreads();
        if (t == 0) carry += tmp[255];
        __syncthreads();
    }
}

__global__ void k_scan3(int* __restrict__ out, const int* __restrict__ bsum, int n, int Etot,
                        int* __restrict__ rp_last, int* __restrict__ cur) {
    int gid = blockIdx.x * 256 + threadIdx.x;
    if (gid < n) {
        int v = out[gid] + bsum[blockIdx.x];
        out[gid] = v;
        cur[gid] = v;
    }
    if (gid == 0) rp_last[0] = Etot;
}

__global__ void k_scatter(const int* __restrict__ src, const int* __restrict__ dst, int E, int Etot,
                          int* __restrict__ cur, int* __restrict__ csrc) {
    int e = blockIdx.x * 256 + threadIdx.x;
    if (e >= Etot) return;
    int s, d;
    esd(src, dst, E, e, s, d);
    int pos = atomicAdd(&cur[d], 1);
    csrc[pos] = s;
}

// ---------------- merged weight prep ----------------
__global__ void k_prep_w(const float* __restrict__ W1, const float* __restrict__ a1s,
                         const float* __restrict__ a1d, const float* __restrict__ W2,
                         __half* __restrict__ W1T, float* __restrict__ wes,
                         float* __restrict__ wed, __half* __restrict__ W2T) {
    int idx = blockIdx.x * 256 + threadIdx.x;
    if (idx < 76800) {
        int h = idx / (80 * 96), r = idx % (80 * 96), c = r / 96, k = r % 96;
        float v = (c < 78 && k < 78) ? W1[(size_t)k * 780 + h * 78 + c] : 0.f;
        W1T[idx] = __float2half(v);
    } else if (idx < 77600) {
        int j = idx - 76800;
        int h = j / 80, k = j % 80;
        float s = 0.f, d = 0.f;
        if (k < 78) {
            for (int f = 0; f < 78; f++) {
                float w = W1[(size_t)k * 780 + h * 78 + f];
                s = fmaf(w, a1s[h * 78 + f], s);
                d = fmaf(w, a1d[h * 78 + f], d);
            }
        }
        wes[j] = s;
        wed[j] = d;
    } else if (idx < 77600 + 128 * 800) {
        int j = idx - 77600;
        int c = j / 800, k = j % 800;
        float v = (k < 780) ? W2[(size_t)k * 128 + c] : 0.f;
        W2T[j] = __float2half(v);
    }
}

// xpk [N][64] half2: {x[c], x[c+64] or 0}
__global__ void k_prep_xpk(const float* __restrict__ x, __half2* __restrict__ xpk, int N) {
    int idx = blockIdx.x * 256 + threadIdx.x;
    if (idx >= N * 64) return;
    int n = idx >> 6, l = idx & 63;
    float lo = x[(size_t)n * 78 + l];
    float hi = (64 + l < 78) ? x[(size_t)n * 78 + 64 + l] : 0.f;
    xpk[idx] = __floats2half2_rn(lo, hi);
}

// es/ed for all 10 heads: esg/edg [N][16]
__global__ void k_coefx(const float* __restrict__ x, const float* __restrict__ wes,
                        const float* __restrict__ wed, float* __restrict__ esg,
                        float* __restrict__ edg, int N) {
    int n = blockIdx.x * 256 + threadIdx.x;
    if (n >= N) return;
    float es[10] = {}, ed[10] = {};
    const float* xr = x + (size_t)n * 78;
    for (int k = 0; k < 78; k++) {
        float xv = xr[k];
#pragma unroll
        for (int h = 0; h < 10; h++) {
            es[h] = fmaf(xv, wes[h * 80 + k], es[h]);
            ed[h] = fmaf(xv, wed[h * 80 + k], ed[h]);
        }
    }
#pragma unroll
    for (int h = 0; h < 10; h++) {
        esg[(size_t)n * 16 + h] = es[h];
        edg[(size_t)n * 16 + h] = ed[h];
    }
}

// ---------------- fused 10-head GAT on x -> xagg [N][10][80] fp16 ----------------
__global__ void k_gatx10(const int* __restrict__ rp, const int* __restrict__ csrc,
                         const float* __restrict__ esg, const float* __restrict__ edg,
                         const __half2* __restrict__ xpk, __half* __restrict__ xagg, int N) {
    __shared__ __align__(16) __half2 pl[4][64][12];
    __shared__ __align__(16) int sl[4][64];
    int w = threadIdx.x >> 6, lane = threadIdx.x & 63;
    int node = blockIdx.x * 4 + w;
    if (node >= N) return;
    int beg = rp[node], end = rp[node + 1];
    int deg = end - beg;

    float edn[10];
    {
        const float* ep = edg + (size_t)node * 16;
        float4 a = *(const float4*)ep, b = *(const float4*)(ep + 4);
        float2 c = *(const float2*)(ep + 8);
        edn[0] = a.x; edn[1] = a.y; edn[2] = a.z; edn[3] = a.w;
        edn[4] = b.x; edn[5] = b.y; edn[6] = b.z; edn[7] = b.w;
        edn[8] = c.x; edn[9] = c.y;
    }

    __half2 acc[10];
#pragma unroll
    for (int h = 0; h < 10; h++) acc[h] = __floats2half2_rn(0.f, 0.f);

#define PASSC_BODY(LIMIT)                                                          \
    for (int i0 = 0; i0 < (LIMIT); i0 += 4) {                                      \
        int4 s4 = *(const int4*)&sl[w][i0];                                        \
        __half2 xr0 = xpk[(size_t)s4.x * 64 + lane];                               \
        __half2 xr1 = xpk[(size_t)s4.y * 64 + lane];                               \
        __half2 xr2 = xpk[(size_t)s4.z * 64 + lane];                               \
        __half2 xr3 = xpk[(size_t)s4.w * 64 + lane];                               \
        _Pragma("unroll")                                                          \
        for (int j = 0; j < 4; j++) {                                              \
            F4H2 qa, qb; F2H2 qc;                                                  \
            qa.f = *(const float4*)&pl[w][i0 + j][0];                              \
            qb.f = *(const float4*)&pl[w][i0 + j][4];                              \
            qc.f = *(const float2*)&pl[w][i0 + j][8];                              \
            __half2 xr = (j == 0) ? xr0 : (j == 1) ? xr1 : (j == 2) ? xr2 : xr3;   \
            acc[0] = __hfma2(qa.h[0], xr, acc[0]);                                 \
            acc[1] = __hfma2(qa.h[1], xr, acc[1]);                                 \
            acc[2] = __hfma2(qa.h[2], xr, acc[2]);                                 \
            acc[3] = __hfma2(qa.h[3], xr, acc[3]);                                 \
            acc[4] = __hfma2(qb.h[0], xr, acc[4]);                                 \
            acc[5] = __hfma2(qb.h[1], xr, acc[5]);                                 \
            acc[6] = __hfma2(qb.h[2], xr, acc[6]);                                 \
            acc[7] = __hfma2(qb.h[3], xr, acc[7]);                                 \
            acc[8] = __hfma2(qc.h[0], xr, acc[8]);                                 \
            acc[9] = __hfma2(qc.h[1], xr, acc[9]);                                 \
        }                                                                          \
    }

#define STASH(PVEC)                                                                \
    {                                                                              \
        F4H2 wa, wb; F2H2 wc;                                                      \
        _Pragma("unroll")                                                          \
        for (int h = 0; h < 4; h++) wa.h[h] = __float2half2_rn(PVEC[h]);           \
        _Pragma("unroll")                                                          \
        for (int h = 0; h < 4; h++) wb.h[h] = __float2half2_rn(PVEC[4 + h]);       \
        wc.h[0] = __float2half2_rn(PVEC[8]);                                       \
        wc.h[1] = __float2half2_rn(PVEC[9]);                                       \
        *(float4*)&pl[w][lane][0] = wa.f;                                          \
        *(float4*)&pl[w][lane][4] = wb.f;                                          \
        *(float2*)&pl[w][lane][8] = wc.f;                                          \
        sl[w][lane] = s;                                                           \
    }

    if (deg <= 64) {
        bool act = lane < deg;
        int s = act ? csrc[beg + lane] : 0;
        float p[10];
        if (act) {
            const float* sp = esg + (size_t)s * 16;
            float4 a = *(const float4*)sp, b = *(const float4*)(sp + 4);
            float2 c = *(const float2*)(sp + 8);
            float v[10];
            v[0] = a.x + edn[0]; v[1] = a.y + edn[1]; v[2] = a.z + edn[2]; v[3] = a.w + edn[3];
            v[4] = b.x + edn[4]; v[5] = b.y + edn[5]; v[6] = b.z + edn[6]; v[7] = b.w + edn[7];
            v[8] = c.x + edn[8]; v[9] = c.y + edn[9];
#pragma unroll
            for (int h = 0; h < 10; h++) {
                float vv = v[h] >= 0.f ? v[h] : 0.2f * v[h];
                p[h] = __expf(vv);
            }
        } else {
#pragma unroll
            for (int h = 0; h < 10; h++) p[h] = 0.f;
        }
        __half2 sh[5];
#pragma unroll
        for (int j = 0; j < 5; j++) sh[j] = __floats2half2_rn(p[2 * j], p[2 * j + 1]);
        int start = (deg <= 16) ? 8 : 32;
        for (int off = start; off; off >>= 1) {
#pragma unroll
            for (int j = 0; j < 5; j++) sh[j] = __hadd2(sh[j], shfl_xor_h2(sh[j], off));
        }
#pragma unroll
        for (int j = 0; j < 5; j++) {
            float2 f = __half22float2(sh[j]);
            p[2 * j] *= 1.f / f.x;
            p[2 * j + 1] *= 1.f / f.y;
        }
        STASH(p)
        PASSC_BODY(deg)
    } else {
        float ssf[10] = {};
        for (int cb = beg; cb < end; cb += 64) {
            int e = cb + lane;
            bool act = e < end;
            int si = act ? csrc[e] : 0;
            if (act) {
                const float* sp = esg + (size_t)si * 16;
#pragma unroll
                for (int h = 0; h < 10; h++) {
                    float vv = sp[h] + edn[h];
                    vv = vv >= 0.f ? vv : 0.2f * vv;
                    ssf[h] += __expf(vv);
                }
            }
        }
#pragma unroll
        for (int off = 32; off; off >>= 1) {
#pragma unroll
            for (int h = 0; h < 10; h++) ssf[h] += __shfl_xor(ssf[h], off);
        }
        float inv[10];
#pragma unroll
        for (int h = 0; h < 10; h++) inv[h] = 1.f / ssf[h];

        for (int cb = beg; cb < end; cb += 64) {
            int cnt = min(64, end - cb);
            int e = cb + lane;
            bool act = e < end;
            int s = act ? csrc[e] : 0;
            float p[10];
            if (act) {
                const float* sp = esg + (size_t)s * 16;
#pragma unroll
                for (int h = 0; h < 10; h++) {
                    float vv = sp[h] + edn[h];
                    vv = vv >= 0.f ? vv : 0.2f * vv;
                    p[h] = __expf(vv) * inv[h];
                }
            } else {
#pragma unroll
                for (int h = 0; h < 10; h++) p[h] = 0.f;
            }
            STASH(p)
            PASSC_BODY(cnt)
        }
    }
#undef PASSC_BODY
#undef STASH

    __half* op = xagg + (size_t)node * 800;
#pragma unroll
    for (int h = 0; h < 10; h++) {
        __half* hp = op + h * 80;
        hp[lane] = __low2half(acc[h]);
        if (lane < 16) hp[64 + lane] = __high2half(acc[h]);
    }
}

// ---------------- fused GEMM chain: 32 rows / 512 thr / 8 waves ----------------
__global__ __launch_bounds__(512) void k_gemmQ(const __half* __restrict__ xagg,
                                               const __half* __restrict__ W1T,
                                               const float* __restrict__ b1,
                                               const __half* __restrict__ W2T,
                                               const float* __restrict__ a2s,
                                               const float* __restrict__ a2d,
                                               __half* __restrict__ h216,
                                               float* __restrict__ es2,
                                               float* __restrict__ ed2, int N) {
    constexpr int LQ = 808;
    __shared__ __align__(16) _Float16 qlds[32 * LQ];  // 50.5 KB; front reused as sered later
    int w = threadIdx.x >> 6, lane = threadIdx.x & 63;
    int row0 = blockIdx.x * 32;
    int col16 = lane & 15, grp = lane >> 4;
    int ko = grp * 8;
    int rbase = grp * 4;

    for (int i = threadIdx.x; i < 32 * 28; i += 512) {
        int r = i / 28, c = 780 + i % 28;
        qlds[r * LQ + c] = (_Float16)0.f;
    }

    // ---- phase 1: job j -> head j>>1, row-half j&1 ----
    for (int j = w; j < 20; j += 8) {
        int h = j >> 1, half = j & 1;
        int ar = min(row0 + half * 16 + col16, N - 1);
        const _Float16* Ap = (const _Float16*)xagg + (size_t)ar * 800 + h * 80 + ko;
        const _Float16* Bp = (const _Float16*)W1T + ((size_t)h * 80 + col16) * 96 + ko;
        f4v acc1[5] = {};
#pragma unroll
        for (int ks = 0; ks < 3; ks++) {
            h8v a = *(const h8v*)(Ap + ks * 32);  // ks=2 overreads next head; W1T zeros cover
#pragma unroll
            for (int t = 0; t < 5; t++) {
                h8v b = *(const h8v*)(Bp + (size_t)t * 16 * 96 + ks * 32);
                acc1[t] = __builtin_amdgcn_mfma_f32_16x16x32_f16(a, b, acc1[t], 0, 0, 0);
            }
        }
#pragma unroll
        for (int t = 0; t < 5; t++) {
            int c = t * 16 + col16;
            if (c < 78) {
                float bias = b1[h * 78 + c];
#pragma unroll
                for (int r = 0; r < 4; r++) {
                    float v = acc1[t][r] + bias;
                    float e = v > 0.f ? v : (__expf(v) - 1.f);
                    qlds[(half * 16 + rbase + r) * LQ + h * 78 + c] = (_Float16)e;
                }
            }
        }
    }
    __syncthreads();

    // ---- phase 2: wave w -> t-tile w over both row-blocks ----
    f4v acc0 = {}, acc1 = {};
    const _Float16* Bq = (const _Float16*)W2T + ((size_t)w * 16 + col16) * 800 + ko;
    const _Float16* Aq0 = qlds + (size_t)col16 * LQ + ko;
    const _Float16* Aq1 = qlds + (size_t)(16 + col16) * LQ + ko;
    for (int ks = 0; ks < 25; ks++) {
        h8v b = *(const h8v*)(Bq + ks * 32);
        h8v a0 = *(const h8v*)(Aq0 + ks * 32);
        h8v a1 = *(const h8v*)(Aq1 + ks * 32);
        acc0 = __builtin_amdgcn_mfma_f32_16x16x32_f16(a0, b, acc0, 0, 0, 0);
        acc1 = __builtin_amdgcn_mfma_f32_16x16x32_f16(a1, b, acc1, 0, 0, 0);
    }
    float wa = a2s[w * 16 + col16], wb = a2d[w * 16 + col16];
    float sse[2][4], ssd[2][4];
#pragma unroll
    for (int rb = 0; rb < 2; rb++) {
#pragma unroll
        for (int r = 0; r < 4; r++) {
            int n = row0 + rb * 16 + rbase + r;
            float v = rb ? acc1[r] : acc0[r];
            float se = v * wa, sd = v * wb;
#pragma unroll
            for (int off = 1; off < 16; off <<= 1) {
                se += __shfl_xor(se, off);
                sd += __shfl_xor(sd, off);
            }
            sse[rb][r] = se;
            ssd[rb][r] = sd;
            if (n < N) h216[(size_t)n * 128 + w * 16 + col16] = __float2half(v);
        }
    }
    __syncthreads();
    float* seredf = (float*)qlds;
    if (col16 == 0) {
#pragma unroll
        for (int rb = 0; rb < 2; rb++) {
#pragma unroll
            for (int r = 0; r < 4; r++) {
                int rowi = rb * 16 + rbase + r;
                seredf[w * 64 + rowi] = sse[rb][r];
                seredf[w * 64 + 32 + rowi] = ssd[rb][r];
            }
        }
    }
    __syncthreads();
    if (threadIdx.x < 32) {
        int n = row0 + threadIdx.x;
        if (n < N) {
            float es = 0.f, ed = 0.f;
#pragma unroll
            for (int ww = 0; ww < 8; ww++) {
                es += seredf[ww * 64 + threadIdx.x];
                ed += seredf[ww * 64 + 32 + threadIdx.x];
            }
            es2[n] = es;
            ed2[n] = ed;
        }
    }
}

// ---------------- layer-2 GAT + relu + block-pooled max -> gb ----------------
__global__ void k_gatP(const int* __restrict__ rp, const int* __restrict__ csrc,
                       const float* __restrict__ es, const float* __restrict__ ed,
                       const __half2* __restrict__ h216, const float* __restrict__ b2,
                       const int* __restrict__ batch, unsigned* __restrict__ gb, int N) {
    __shared__ float red[4][128];
    __shared__ int bids[4];
    __shared__ __align__(16) __half2 plP[4][64];
    __shared__ __align__(16) int slP[4][64];
    int w = threadIdx.x >> 6, lane = threadIdx.x & 63;
    int node = blockIdx.x * 4 + w;
    bool valid = node < N;

    __half2 acc = __floats2half2_rn(0.f, 0.f);
    int bid = -1;

#define PASSC2(LIMIT)                                                      \
    for (int i0 = 0; i0 < (LIMIT); i0 += 4) {                              \
        int4 s4 = *(const int4*)&slP[w][i0];                               \
        F4H2 q; q.f = *(const float4*)&plP[w][i0];                         \
        __half2 f0 = h216[(size_t)s4.x * 64 + lane];                       \
        __half2 f1 = h216[(size_t)s4.y * 64 + lane];                       \
        __half2 f2 = h216[(size_t)s4.z * 64 + lane];                       \
        __half2 f3 = h216[(size_t)s4.w * 64 + lane];                       \
        acc = __hfma2(q.h[0], f0, acc);                                    \
        acc = __hfma2(q.h[1], f1, acc);                                    \
        acc = __hfma2(q.h[2], f2, acc);                                    \
        acc = __hfma2(q.h[3], f3, acc);                                    \
    }

    if (valid) {
        int beg = rp[node], end = rp[node + 1];
        int deg = end - beg;
        float edn = ed[node];
        bid = batch[node];

        if (deg <= 64) {
            bool act = lane < deg;
            int s = act ? csrc[beg + lane] : 0;
            float p = 0.f;
            if (act) {
                float v = es[s] + edn;
                v = v >= 0.f ? v : 0.2f * v;
                p = __expf(v);
            }
            float ss = p;
            int start = (deg <= 16) ? 8 : 32;
            for (int off = start; off; off >>= 1) ss += __shfl_xor(ss, off);
            p *= 1.f / ss;
            plP[w][lane] = __float2half2_rn(p);
            slP[w][lane] = s;
            PASSC2(deg)
        } else {
            float ss = 0.f;
            for (int cb = beg; cb < end; cb += 64) {
                int e = cb + lane;
                bool act = e < end;
                int s = act ? csrc[e] : 0;
                if (act) {
                    float v = es[s] + edn;
                    v = v >= 0.f ? v : 0.2f * v;
                    ss += __expf(v);
                }
            }
#pragma unroll
            for (int off = 32; off; off >>= 1) ss += __shfl_xor(ss, off);
            float inv = 1.f / ss;
            for (int cb = beg; cb < end; cb += 64) {
                int cnt = min(64, end - cb);
                int e = cb + lane;
                bool act = e < end;
                int s = act ? csrc[e] : 0;
                float p = 0.f;
                if (act) {
                    float v = es[s] + edn;
                    v = v >= 0.f ? v : 0.2f * v;
                    p = __expf(v) * inv;
                }
                plP[w][lane] = __float2half2_rn(p);
                slP[w][lane] = s;
                PASSC2(cnt)
            }
        }
    }
#undef PASSC2

    float2 af = __half22float2(acc);
    red[w][2 * lane]     = valid ? fmaxf(af.x + b2[2 * lane], 0.f) : 0.f;
    red[w][2 * lane + 1] = valid ? fmaxf(af.y + b2[2 * lane + 1], 0.f) : 0.f;
    if (lane == 0) bids[w] = valid ? bid : -1;
    __syncthreads();
    if (threadIdx.x < 128) {
        int c = threadIdx.x;
        int b0 = bids[0];
        bool same = (bids[1] == b0) && (bids[2] == b0) && (bids[3] == b0);
        if (same && b0 >= 0) {
            float m = fmaxf(fmaxf(red[0][c], red[1][c]), fmaxf(red[2][c], red[3][c]));
            atomicMax(&gb[(size_t)b0 * 128 + c], __float_as_uint(m));
        } else {
#pragma unroll
            for (int w2 = 0; w2 < 4; w2++) {
                if (bids[w2] >= 0)
                    atomicMax(&gb[(size_t)bids[w2] * 128 + c], __float_as_uint(red[w2][c]));
            }
        }
    }
}

// ---------------- fused head part 1 ----------------
__global__ void k_head_gxt(const unsigned* __restrict__ gbits, const float* __restrict__ Wg,
                           const float* __restrict__ bg, const float* __restrict__ te,
                           const float* __restrict__ Wxt, const float* __restrict__ bxt,
                           const float* __restrict__ gamma, const float* __restrict__ beta,
                           const float* __restrict__ rmean, const float* __restrict__ rvar,
                           float* __restrict__ xc) {
    __shared__ float sg[F2];
    __shared__ float st[EMB];
    int b = blockIdx.x, t = threadIdx.x;
    if (t < 128) {
        sg[t] = __uint_as_float(gbits[(size_t)b * F2 + t]);
    } else {
        for (int k = t - 128; k < EMB; k += 128) st[k] = te[(size_t)b * EMB + k];
    }
    __syncthreads();
    if (t < 128) {
        float acc = bg[t];
        for (int k = 0; k < F2; k++) acc = fmaf(sg[k], Wg[k * F2 + t], acc);
        xc[(size_t)b * 256 + t] = fmaxf(acc, 0.f);
    } else {
        int c = t - 128;
        float acc = bxt[c];
        for (int k = 0; k < EMB; k++) acc = fmaf(st[k], Wxt[k * F2 + c], acc);
        acc = (acc - rmean[c]) * rsqrtf(rvar[c] + 1e-5f) * gamma[c] + beta[c];
        xc[(size_t)b * 256 + 128 + c] = fmaxf(acc, 0.f);
    }
}

// ---------------- head f1: grid (B,4) x 256 thr, one col/thread ----------------
__global__ void k_head_f1(const float* __restrict__ xc, const float* __restrict__ Wf1,
                          const float* __restrict__ bf1, float* __restrict__ f1o) {
    __shared__ float srow[256];
    int b = blockIdx.x, t = threadIdx.x;
    srow[t] = xc[(size_t)b * 256 + t];
    __syncthreads();
    int col = blockIdx.y * 256 + t;
    float a0 = 0.f, a1 = 0.f, a2 = 0.f, a3 = 0.f;
    for (int k = 0; k < 256; k += 4) {
        a0 = fmaf(srow[k + 0], Wf1[(size_t)(k + 0) * 1024 + col], a0);
        a1 = fmaf(srow[k + 1], Wf1[(size_t)(k + 1) * 1024 + col], a1);
        a2 = fmaf(srow[k + 2], Wf1[(size_t)(k + 2) * 1024 + col], a2);
        a3 = fmaf(srow[k + 3], Wf1[(size_t)(k + 3) * 1024 + col], a3);
    }
    float acc = ((a0 + a1) + (a2 + a3)) + bf1[col];
    f1o[(size_t)b * 1024 + col] = fmaxf(acc, 0.f);
}

// ---------------- head f2 + out: grid (B,4) x 64 thr; atomicAdd partials into out ----------------
__global__ void k_head_f2o(const float* __restrict__ f1o, const float* __restrict__ Wf2,
                           const float* __restrict__ bf2, const float* __restrict__ Wo,
                           const float* __restrict__ bo, float* __restrict__ out) {
    __shared__ float srow[1024];
    int b = blockIdx.x, t = threadIdx.x;
    for (int k = t; k < 1024; k += 64) srow[k] = f1o[(size_t)b * 1024 + k];
    __syncthreads();
    int col = blockIdx.y * 64 + t;
    float a0 = 0.f, a1 = 0.f, a2 = 0.f, a3 = 0.f;
    for (int k = 0; k < 1024; k += 4) {
        a0 = fmaf(srow[k + 0], Wf2[(size_t)(k + 0) * 256 + col], a0);
        a1 = fmaf(srow[k + 1], Wf2[(size_t)(k + 1) * 256 + col], a1);
        a2 = fmaf(srow[k + 2], Wf2[(size_t)(k + 2) * 256 + col], a2);
        a3 = fmaf(srow[k + 3], Wf2[(size_t)(k + 3) * 256 + col], a3);
    }
    float v = fmaxf(((a0 + a1) + (a2 + a3)) + bf2[col], 0.f) * Wo[col];
    for (int off = 32; off; off >>= 1) v += __shfl_down(v, off);
    if (t == 0) {
        float add = v + (blockIdx.y == 0 ? bo[0] : 0.f);
        atomicAdd(&out[b], add);
    }
}

extern "C" void kernel_launch(void* const* d_in, const int* in_sizes, int n_in,
                              void* d_out, int out_size, void* d_ws, size_t ws_size,
                              hipStream_t stream) {
    const float* x     = (const float*)d_in[0];
    const int*   ei    = (const int*)d_in[1];
    const int*   batch = (const int*)d_in[2];
    const float* te    = (const float*)d_in[3];
    const float* W1    = (const float*)d_in[4];
    const float* a1s   = (const float*)d_in[5];
    const float* a1d   = (const float*)d_in[6];
    const float* b1    = (const float*)d_in[7];
    const float* W2    = (const float*)d_in[8];
    const float* a2s   = (const float*)d_in[9];
    const float* a2d   = (const float*)d_in[10];
    const float* b2    = (const float*)d_in[11];
    const float* Wg    = (const float*)d_in[12];
    const float* bg    = (const float*)d_in[13];
    const float* Wxt   = (const float*)d_in[14];
    const float* bxt   = (const float*)d_in[15];
    const float* gamma = (const float*)d_in[16];
    const float* beta  = (const float*)d_in[17];
    const float* rmean = (const float*)d_in[18];
    const float* rvar  = (const float*)d_in[19];
    const float* Wf1   = (const float*)d_in[20];
    const float* bf1   = (const float*)d_in[21];
    const float* Wf2   = (const float*)d_in[22];
    const float* bf2   = (const float*)d_in[23];
    const float* Wo    = (const float*)d_in[24];
    const float* bo    = (const float*)d_in[25];

    const int N = in_sizes[0] / 78;
    const int E = in_sizes[1] / 2;
    const int B = in_sizes[3] / EMB;
    const int Etot = E + N;
    const int* src = ei;
    const int* dst = ei + E;

    char* p = (char*)d_ws;
    auto alloc = [&](size_t bytes) -> void* {
        void* r = p;
        p += (bytes + 255) & ~(size_t)255;
        return r;
    };
    __half2*  xpk  = (__half2*)alloc((size_t)N * 64 * 4);
    __half*   xagg = (__half*)alloc((size_t)N * 800 * 2 + 256);
    __half*   h216 = (__half*)alloc((size_t)N * 128 * 2);
    float*    esg  = (float*)alloc((size_t)N * 16 * 4);
    float*    edg  = (float*)alloc((size_t)N * 16 * 4);
    float*    es2  = (float*)alloc((size_t)N * 4);
    float*    ed2  = (float*)alloc((size_t)N * 4);
    __half*   W1T  = (__half*)alloc((size_t)10 * 80 * 96 * 2);
    __half*   W2T  = (__half*)alloc((size_t)128 * 800 * 2);
    float*    wes  = (float*)alloc((size_t)800 * 4);
    float*    wed  = (float*)alloc((size_t)800 * 4);
    int*      cnt  = (int*)alloc((size_t)N * 4);
    int*      rp   = (int*)alloc((size_t)(N + 1) * 4);
    int*      cur  = (int*)alloc((size_t)N * 4);
    int*      csrc = (int*)alloc((size_t)Etot * 4);
    int*      bsum = (int*)alloc((size_t)1024 * 4);
    unsigned* gb   = (unsigned*)alloc((size_t)B * F2 * 4);
    float*    xc   = (float*)alloc((size_t)B * 256 * 4);
    float*    f1o  = (float*)alloc((size_t)B * 1024 * 4);

    auto gsz = [](long long t) { return (int)((t + 255) / 256); };
    const int nb = gsz(N);
    const int nwave = (N + 3) / 4;
    const int nrow32 = (N + 31) / 32;

    // ---- CSR build ----
    hipMemsetAsync(cnt, 0, (size_t)N * 4, stream);
    k_count<<<gsz(Etot), 256, 0, stream>>>(src, dst, E, Etot, cnt);
    k_scan1<<<nb, 256, 0, stream>>>(cnt, rp, bsum, N);
    k_scan2<<<1, 256, 0, stream>>>(bsum, nb);
    k_scan3<<<nb, 256, 0, stream>>>(rp, bsum, N, Etot, rp + N, cur);
    k_scatter<<<gsz(Etot), 256, 0, stream>>>(src, dst, E, Etot, cur, csrc);

    // ---- prep ----
    k_prep_w<<<gsz(77600 + 128 * 800), 256, 0, stream>>>(W1, a1s, a1d, W2, W1T, wes, wed, W2T);
    k_prep_xpk<<<gsz((long long)N * 64), 256, 0, stream>>>(x, xpk, N);
    k_coefx<<<nb, 256, 0, stream>>>(x, wes, wed, esg, edg, N);
    hipMemsetAsync(gb, 0, (size_t)B * F2 * 4, stream);
    hipMemsetAsync(d_out, 0, (size_t)out_size * 4, stream);

    // ---- GAT layer 1 (all 10 heads) ----
    k_gatx10<<<nwave, 256, 0, stream>>>(rp, csrc, esg, edg, xpk, xagg, N);

    // ---- fused GEMM chain ----
    k_gemmQ<<<nrow32, 512, 0, stream>>>(xagg, W1T, b1, W2T, a2s, a2d, h216, es2, ed2, N);

    // ---- GAT layer 2 + fused pool ----
    k_gatP<<<nwave, 256, 0, stream>>>(rp, csrc, es2, ed2, (const __half2*)h216, b2, batch, gb, N);

    // ---- head: gxt -> f1 (B x 4 blocks) -> f2+out (B x 4 blocks, atomic partials) ----
    k_head_gxt<<<B, 256, 0, stream>>>(gb, Wg, bg, te, Wxt, bxt, gamma, beta, rmean, rvar, xc);
    k_head_f1<<<dim3(B, 4), 256, 0, stream>>>(xc, Wf1, bf1, f1o);
    k_head_f2o<<<dim3(B, 4), 64, 0, stream>>>(f1o, Wf2, bf2, Wo, bo, (float*)d_out);
}